// Round 9
// baseline (557.407 us; speedup 1.0000x reference)
//
#include <hip/hip_runtime.h>
#include <cstdint>
#include <cstddef>

// ---------- types / helpers ----------
typedef __bf16 bf16x8 __attribute__((ext_vector_type(8)));
typedef float  floatx4 __attribute__((ext_vector_type(4)));
typedef unsigned short ushort8 __attribute__((ext_vector_type(8)));
typedef unsigned short ushort4v __attribute__((ext_vector_type(4)));

__device__ __forceinline__ float bf2f(unsigned short u) {
    union { unsigned int u32; float f; } x; x.u32 = ((unsigned int)u) << 16; return x.f;
}
__device__ __forceinline__ float bflo(unsigned int u) {
    union { unsigned int u32; float f; } x; x.u32 = u << 16; return x.f;
}
__device__ __forceinline__ float bfhi(unsigned int u) {
    union { unsigned int u32; float f; } x; x.u32 = u & 0xffff0000u; return x.f;
}
__device__ __forceinline__ unsigned short f2bf(float f) {
    union { float f; unsigned int u; } x; x.f = f;
    unsigned int u = x.u;
    unsigned int r = (u + 0x7fffu + ((u >> 16) & 1u)) >> 16;   // RNE
    return (unsigned short)r;
}

#define GLOBAL_U32 const __attribute__((address_space(1))) unsigned int*
#define LDS_U32 __attribute__((address_space(3))) unsigned int*
__device__ __forceinline__ void async_cp16(const void* g, void* l) {
    __builtin_amdgcn_global_load_lds((GLOBAL_U32)g, (LDS_U32)l, 16, 0, 0);
}

// ---------- conv1 (oh-split x2): x[256,1,28,28]*w[256,1,9,9] -> h1t bf16 [b][20][20][256] ----------
__global__ __launch_bounds__(256) void conv1_k(const float* __restrict__ x,
                                               const float* __restrict__ w,
                                               const float* __restrict__ bias,
                                               unsigned short* __restrict__ h1t) {
    const int bb = blockIdx.x, t = threadIdx.x;
    const int b = bb >> 1, h = bb & 1;
    const int oh0 = h * 10;
    __shared__ float xs[18 * 28];
    for (int idx = t; idx < 504; idx += 256) xs[idx] = x[b * 784 + oh0 * 28 + idx];
    __syncthreads();
    const float* wr = w + t * 81;   // thread t = output channel t
    const float bv = bias[t];
    for (int ohl = 0; ohl < 10; ++ohl) {
        float acc[20];
#pragma unroll
        for (int ow = 0; ow < 20; ++ow) acc[ow] = bv;
#pragma unroll
        for (int kh = 0; kh < 9; ++kh) {
            float xr[28];
            const float* xrow = &xs[(ohl + kh) * 28];
#pragma unroll
            for (int q = 0; q < 7; ++q) *(float4*)&xr[q * 4] = *(const float4*)&xrow[q * 4];
#pragma unroll
            for (int kw = 0; kw < 9; ++kw) {
                const float wv = wr[kh * 9 + kw];
#pragma unroll
                for (int ow = 0; ow < 20; ++ow) acc[ow] = fmaf(xr[ow + kw], wv, acc[ow]);
            }
        }
        unsigned short* orow = h1t + (size_t)((b * 20 + oh0 + ohl) * 20) * 256 + t;
#pragma unroll
        for (int ow = 0; ow < 20; ++ow) orow[ow * 256] = f2bf(acc[ow]);
    }
}

// ---------- w2 transform: OIHW fp32 [oc][ic][81] -> bf16 [oc][tap*256+ic] ----------
__global__ __launch_bounds__(256) void w2t_k(const float* __restrict__ w2,
                                             unsigned short* __restrict__ w2t) {
    const int oc = blockIdx.x >> 1, half = blockIdx.x & 1, t = threadIdx.x;
    __shared__ float ws[10368];                       // 128 ic * 81 taps
    const float* src = w2 + (size_t)oc * 20736 + half * 128 * 81;
    for (int idx = t; idx < 10368; idx += 256) ws[idx] = src[idx];
    __syncthreads();
    unsigned short* dst = w2t + (size_t)oc * 20736 + half * 128;
    for (int idx = t; idx < 10368; idx += 256) {
        const int tap = idx >> 7, icl = idx & 127;
        dst[tap * 256 + icl] = f2bf(ws[icl * 81 + tap]);
    }
}

// ---------- conv2 implicit GEMM: tile 128M x 64OC, split-K x4, BK=64, swizzled LDS ----------
__device__ __forceinline__ int c2_rowbase(int m) {
    const int b = m / 36, sp = m % 36;
    const int oh = sp / 6, ow = sp % 6;
    return (b * 400 + oh * 40 + ow * 2) * 256;        // element offset into h1t
}

__global__ __launch_bounds__(256) void conv2_k(const unsigned short* __restrict__ h1t,
                                               const unsigned short* __restrict__ w2t,
                                               unsigned short* __restrict__ part) {
    const int t = threadIdx.x;
    // 1152 ids: the 4 bx-siblings of one (by,z) sit 8 apart (same XCD under
    // round-robin) -> A-slice fetched once per XCD; z decorrelated from XCD.
    const int id = blockIdx.x;                        // 0..1151
    const int G = id >> 5;                            // 0..35
    const int bx = (id >> 3) & 3;                     // 0..3 (64-oc tile)
    const int s = id & 7;
    const int by = 2 * G + (s >> 2);                  // 0..71
    const int z  = ((s & 3) + by) & 3;                // 0..3
    __shared__ unsigned short At[128 * 64];           // m rows (16 KB)
    __shared__ unsigned short Bt[64 * 64];            // oc rows (8 KB)

    const int oc0 = bx * 64;

    // staging: A = 4 units/thread, B = 2 units/thread (16B each).
    // LDS slot a; row = a>>3, phys slot sγ = a&7 holds logical unit
    // u = sγ ^ (row&7)  (bank-conflict-free b128 reads).
    int aRB[4], aCU[4], bBase[2];
#pragma unroll
    for (int k = 0; k < 4; ++k) {
        const int a = t + 256 * k;
        const int r = a >> 3, sg = a & 7;
        const int u = sg ^ (r & 7);
        aRB[k] = c2_rowbase(by * 128 + r) + (u & 3) * 8;
        aCU[k] = u >> 2;                              // which chunk of the pair
    }
#pragma unroll
    for (int k = 0; k < 2; ++k) {
        const int a = t + 256 * k;
        const int r = a >> 3, sg = a & 7;             // r in 0..63
        const int u = sg ^ (r & 7);
        bBase[k] = (oc0 + r) * 20736 + (u >> 2) * 32 + (u & 3) * 8;
    }

    const int lane = t & 63, l15 = lane & 15, quad = lane >> 4;
    const int wave = t >> 6;
    const int wM = (wave & 1) * 64, wOC = (wave >> 1) * 32;

    // fragment LDS offsets (ushort units): row stride 64, unit u = h*4+quad
    int aO[2][2], bO[2][4];
#pragma unroll
    for (int i = 0; i < 2; ++i) {
        const int R = wOC + i * 16 + l15;             // oc row (A-operand from Bt)
#pragma unroll
        for (int h = 0; h < 2; ++h)
            aO[h][i] = R * 64 + (((h * 4 + quad) ^ (R & 7)) << 3);
    }
#pragma unroll
    for (int j = 0; j < 4; ++j) {
        const int R = wM + j * 16 + l15;              // m row (B-operand from At)
#pragma unroll
        for (int h = 0; h < 2; ++h)
            bO[h][j] = R * 64 + (((h * 4 + quad) ^ (R & 7)) << 3);
    }

    floatx4 acc[2][4];
#pragma unroll
    for (int i = 0; i < 2; ++i)
#pragma unroll
        for (int j = 0; j < 4; ++j) acc[i][j] = (floatx4){0.f, 0.f, 0.f, 0.f};

    // K = 648 chunks = 324 pairs; split 4 ways: 81 pairs per z
    const int p0 = 81 * z, p1 = p0 + 81;
    for (int p = p0; p < p1; ++p) {
        const int tap = p >> 2;                       // both chunks of a pair share tap
        const int kh = tap / 9, kw = tap - 9 * kh;
        const int aoffB = (kh * 20 + kw) * 256;
        const int ce7 = (2 * p) & 7;
        __syncthreads();
#pragma unroll
        for (int k = 0; k < 4; ++k)
            async_cp16(h1t + aRB[k] + aoffB + (ce7 + aCU[k]) * 32, At + (t + 256 * k) * 8);
#pragma unroll
        for (int k = 0; k < 2; ++k)
            async_cp16(w2t + bBase[k] + p * 64, Bt + (t + 256 * k) * 8);
        __syncthreads();
#pragma unroll
        for (int h = 0; h < 2; ++h) {
            bf16x8 aF[2], bF[4];
#pragma unroll
            for (int i = 0; i < 2; ++i) aF[i] = *(const bf16x8*)(Bt + aO[h][i]);
#pragma unroll
            for (int j = 0; j < 4; ++j) bF[j] = *(const bf16x8*)(At + bO[h][j]);
#pragma unroll
            for (int i = 0; i < 2; ++i)
#pragma unroll
                for (int j = 0; j < 4; ++j)
                    acc[i][j] = __builtin_amdgcn_mfma_f32_16x16x32_bf16(aF[i], bF[j], acc[i][j], 0, 0, 0);
        }
    }

    // epilogue: D[reg->oc][lane->m]; pack 4 bf16 along n, store to PART[z][m][n]
    unsigned short* pz = part + (size_t)z * 2359296;
#pragma unroll
    for (int i = 0; i < 2; ++i) {
        const int n0 = oc0 + wOC + i * 16 + quad * 4;
#pragma unroll
        for (int j = 0; j < 4; ++j) {
            const int m = by * 128 + wM + j * 16 + l15;
            ushort4v pk;
#pragma unroll
            for (int r = 0; r < 4; ++r) pk[r] = f2bf(acc[i][j][r]);
            *(ushort4v*)(pz + (size_t)m * 256 + n0) = pk;
        }
    }
}

// ---------- reduce split-K(bf16 x4) + bias + squash(axis=w) -> u[b][1152][8] (half-split x2) ----------
__global__ __launch_bounds__(256) void squash_u_k(const unsigned short* __restrict__ part,
                                                  const float* __restrict__ bias,
                                                  float* __restrict__ u) {
    const int bb = blockIdx.x, t = threadIdx.x;
    const int b = bb >> 1, h = bb & 1;
    __shared__ float hs[4608];
    const size_t base = (size_t)b * 9216 + h * 4608;
    for (int q = t; q < 2304; q += 256) {
        const int idx = q * 2;
        float v0 = bias[idx & 255], v1 = bias[(idx + 1) & 255];
#pragma unroll
        for (int z = 0; z < 4; ++z) {
            const unsigned int uu = *(const unsigned int*)(part + (size_t)z * 2359296 + base + idx);
            v0 += bflo(uu);
            v1 += bfhi(uu);
        }
        hs[idx] = v0; hs[idx + 1] = v1;
    }
    __syncthreads();
    for (int gq = t; gq < 768; gq += 256) {           // groups (c, oh-local), squash over ow(6)
        const int c = gq / 3, ohl = gq % 3;
        const int oh = h * 3 + ohl;
        float s[6], sq = 0.f;
#pragma unroll
        for (int ow = 0; ow < 6; ++ow) { s[ow] = hs[(ohl * 6 + ow) * 256 + c]; sq = fmaf(s[ow], s[ow], sq); }
        const float norm = sqrtf(sq);
        const float f = (sq / (1.0f + sq)) / (norm + 1e-7f);
        float* up = u + (size_t)b * 9216 + c * 36 + oh * 6;
#pragma unroll
        for (int ow = 0; ow < 6; ++ow) up[ow] = s[ow] * f;
    }
}

// ---------- u_hat[b][i][o*16+d] bf16 = sum_e W[o,i,d,e]*u[b,i,e] ----------
__global__ __launch_bounds__(256) void uhat_k(const float* __restrict__ Wc,
                                              const float* __restrict__ u,
                                              unsigned short* __restrict__ uhat) {
    const int i = blockIdx.x, t = threadIdx.x;       // t = b
    __shared__ float Wl[1280];                       // [o][d*8+e]
    __shared__ unsigned short Ul[128 * 168];         // padded transpose buffer (43 KB)
    for (int idx = t; idx < 1280; idx += 256) {
        const int o = idx >> 7, r = idx & 127;
        Wl[idx] = Wc[((size_t)o * 1152 + i) * 128 + r];
    }
    float ur[8];
    *(float4*)&ur[0] = *(const float4*)(u + (size_t)t * 9216 + i * 8);
    *(float4*)&ur[4] = *(const float4*)(u + (size_t)t * 9216 + i * 8 + 4);
    __syncthreads();
    unsigned short val[160];
#pragma unroll 1
    for (int o = 0; o < 10; ++o) {
#pragma unroll
        for (int d = 0; d < 16; ++d) {
            const float* wp = &Wl[o * 128 + d * 8];
            float a = 0.f;
#pragma unroll
            for (int e = 0; e < 8; ++e) a = fmaf(wp[e], ur[e], a);
            val[o * 16 + d] = f2bf(a);
        }
    }
#pragma unroll 1
    for (int h = 0; h < 2; ++h) {
        __syncthreads();
        if ((t >> 7) == h) {
            unsigned short* row = &Ul[(t & 127) * 168];
#pragma unroll
            for (int q = 0; q < 20; ++q) *(ushort8*)(row + q * 8) = *(const ushort8*)(val + q * 8);
        }
        __syncthreads();
        for (int idx = t; idx < 2560; idx += 256) {
            const int r = idx / 20, q = idx % 20;
            const int b = h * 128 + r;
            *(ushort8*)(uhat + ((size_t)b * 1152 + i) * 160 + q * 8) =
                *(const ushort8*)(&Ul[r * 168 + q * 8]);
        }
    }
}

// ---------- routing iteration 0: S0[b][160] = 0.1 * sum_i u_hat ----------
__global__ __launch_bounds__(256) void route_iter0_k(const unsigned int* __restrict__ uhat32,
                                                     float* __restrict__ S0) {
    const int b = blockIdx.x, i0 = blockIdx.y * 128, t = threadIdx.x;
    const int th = t & 127, hi = t >> 7;
    if (th >= 80) return;
    const unsigned int* p = uhat32 + ((size_t)b * 1152 + i0 + hi * 64) * 80 + th;
    float ax = 0.f, ay = 0.f;
#pragma unroll 8
    for (int i = 0; i < 64; ++i) {
        const unsigned int uu = p[i * 80];
        ax += bflo(uu);
        ay += bfhi(uu);
    }
    atomicAdd(&S0[b * 160 + 2 * th], 0.1f * ax);
    atomicAdd(&S0[b * 160 + 2 * th + 1], 0.1f * ay);
}

// ---------- fused routing iteration: squash(S_in) + logit update + softmax + weighted sum ----------
template <int ITER>
__global__ __launch_bounds__(256) void route_iter_k(const unsigned short* __restrict__ uhat,
                                                    const float* __restrict__ S_in,
                                                    float* __restrict__ BL,
                                                    float* __restrict__ S_out) {
    const int b = blockIdx.x, i0 = blockIdx.y * 128, t = threadIdx.x;
    __shared__ __align__(16) unsigned short Ul[128 * 160];   // 40960 B
    __shared__ float Vl[160];
    __shared__ float cT[10 * 132];
    __shared__ float dots[128 * 10];

    const char* gsrc = (const char*)(uhat + ((size_t)b * 1152 + i0) * 160);
#pragma unroll
    for (int rep = 0; rep < 10; ++rep)
        async_cp16(gsrc + rep * 4096 + t * 16, (char*)Ul + rep * 4096 + t * 16);

    // phase 0: squash S_in -> Vl (redundant per block; 160 floats)
    if (t < 160) {
        const float x = S_in[b * 160 + t];
        float sq = x * x;
        sq += __shfl_xor(sq, 1, 16);
        sq += __shfl_xor(sq, 2, 16);
        sq += __shfl_xor(sq, 4, 16);
        sq += __shfl_xor(sq, 8, 16);
        const float norm = sqrtf(sq);
        const float f = (sq / (1.f + sq)) / (norm + 1e-7f);
        Vl[t] = x * f;
    }
    __syncthreads();                                  // drains async + Vl visible

    // p1a mapping: o = t%10 fixed per thread, strip s = t/10 (250 active)
    const int o = t % 10, s = t / 10;
    float vr[16];
    if (t < 250) {
#pragma unroll
        for (int q = 0; q < 4; ++q)
            *(float4*)&vr[q * 4] = *(const float4*)(&Vl[o * 16 + q * 4]);
    }

    // p1a: dots[i][o] = sum_d u_hat[i,o,d] * v[o,d]
    if (t < 250) {
#pragma unroll
        for (int rep = 0; rep < 6; ++rep) {
            const int i = s + 25 * rep;
            if (i < 128) {
                const ushort8 ua = *(const ushort8*)(Ul + i * 160 + o * 16);
                const ushort8 ub = *(const ushort8*)(Ul + i * 160 + o * 16 + 8);
                float dot = 0.f;
#pragma unroll
                for (int d = 0; d < 8; ++d) dot = fmaf(bf2f(ua[d]), vr[d], dot);
#pragma unroll
                for (int d = 0; d < 8; ++d) dot = fmaf(bf2f(ub[d]), vr[8 + d], dot);
                dots[i * 10 + o] = dot;
            }
        }
    }
    __syncthreads();

    // p1b: per-i logits + softmax -> cT[o][i]
    if (t < 128) {
        float bl[10];
#pragma unroll
        for (int oo = 0; oo < 10; ++oo) bl[oo] = dots[t * 10 + oo];
        if (ITER == 2) {
#pragma unroll
            for (int oo = 0; oo < 10; ++oo) bl[oo] += BL[(size_t)b * 11520 + oo * 1152 + i0 + t];
        } else {
#pragma unroll
            for (int oo = 0; oo < 10; ++oo) BL[(size_t)b * 11520 + oo * 1152 + i0 + t] = bl[oo];
        }
        float mx = bl[0];
#pragma unroll
        for (int oo = 1; oo < 10; ++oo) mx = fmaxf(mx, bl[oo]);
        float ex[10], sum = 0.f;
#pragma unroll
        for (int oo = 0; oo < 10; ++oo) { ex[oo] = expf(bl[oo] - mx); sum += ex[oo]; }
        const float inv = 1.f / sum;
#pragma unroll
        for (int oo = 0; oo < 10; ++oo) cT[oo * 132 + t] = ex[oo] * inv;
    }
    __syncthreads();

    // p2: S_out[b][160] += sum_i c[i][o] * u_hat[i][od]  (two 64-i halves)
    const int th = t & 127, hi = t >> 7;
    if (th < 80) {
        const int o8 = th >> 3;
        const unsigned int* base = (const unsigned int*)Ul + (size_t)hi * 64 * 80 + th;
        const float* cb = &cT[o8 * 132 + hi * 64];
        float ax = 0.f, ay = 0.f;
#pragma unroll 4
        for (int ii = 0; ii < 64; ++ii) {
            const float c = cb[ii];
            const unsigned int uu = base[ii * 80];
            ax = fmaf(c, bflo(uu), ax);
            ay = fmaf(c, bfhi(uu), ay);
        }
        atomicAdd(&S_out[b * 160 + 2 * th], ax);
        atomicAdd(&S_out[b * 160 + 2 * th + 1], ay);
    }
}

// ---------- final: squash S2 -> lengths, argmax + fused decoder layer 1 ----------
__global__ __launch_bounds__(512) void final_k(const float* __restrict__ S,
                                               const float* __restrict__ w1,
                                               const float* __restrict__ b1,
                                               float* __restrict__ out_len,
                                               float* __restrict__ h1d) {
    const int b = blockIdx.x, t = threadIdx.x;
    __shared__ float v_s[160];
    __shared__ float len_s[10];
    __shared__ int sel_s;
    if (t < 160) {
        const float x = S[b * 160 + t];
        float sq = x * x;
        sq += __shfl_xor(sq, 1, 16);
        sq += __shfl_xor(sq, 2, 16);
        sq += __shfl_xor(sq, 4, 16);
        sq += __shfl_xor(sq, 8, 16);
        const float norm = sqrtf(sq);
        const float f = (sq / (1.f + sq)) / (norm + 1e-7f);
        v_s[t] = x * f;
        if ((t & 15) == 0) {
            const float len = f * norm;
            len_s[t >> 4] = len;
            out_len[b * 10 + (t >> 4)] = len;
        }
    }
    __syncthreads();
    if (t == 0) {
        float best = len_s[0]; int bi = 0;
        for (int oo = 1; oo < 10; ++oo) if (len_s[oo] > best) { best = len_s[oo]; bi = oo; }
        sel_s = bi;
    }
    __syncthreads();
    const int s = sel_s;
    float acc = b1[t];
    const float* wrow = w1 + (size_t)(s * 16) * 512 + t;
#pragma unroll
    for (int j = 0; j < 16; ++j) acc = fmaf(v_s[s * 16 + j], wrow[j * 512], acc);
    h1d[(size_t)b * 512 + t] = fmaxf(acc, 0.f);
}

// ---------- generic small fp32 GEMM + act (M=256 fixed) ----------
template <int ACT>
__global__ __launch_bounds__(256) void mlp_k(const float* __restrict__ A,
                                             const float* __restrict__ Bm,
                                             const float* __restrict__ bias,
                                             float* __restrict__ C, int N, int K) {
    __shared__ float As[64 * 16];
    __shared__ float Bs[16 * 64];
    const int t = threadIdx.x;
    const int tx = t & 15, ty = t >> 4;
    const int m0 = blockIdx.y * 64, n0 = blockIdx.x * 64;
    float acc[4][4] = {};
    const int arow = t >> 2, ac4 = (t & 3) * 4;
    const int brow = t >> 4, bc4 = (t & 15) * 4;
    for (int k0 = 0; k0 < K; k0 += 16) {
        __syncthreads();
        *(float4*)&As[arow * 16 + ac4] = *(const float4*)&A[(size_t)(m0 + arow) * K + k0 + ac4];
        float4 bv = {0.f, 0.f, 0.f, 0.f};
        const int bn = n0 + bc4;
        if (bn + 3 < N) bv = *(const float4*)&Bm[(size_t)(k0 + brow) * N + bn];
        *(float4*)&Bs[brow * 64 + bc4] = bv;
        __syncthreads();
#pragma unroll
        for (int k = 0; k < 16; ++k) {
            float av[4], bvv[4];
#pragma unroll
            for (int r = 0; r < 4; ++r) av[r] = As[(ty * 4 + r) * 16 + k];
#pragma unroll
            for (int c = 0; c < 4; ++c) bvv[c] = Bs[k * 64 + tx * 4 + c];
#pragma unroll
            for (int r = 0; r < 4; ++r)
#pragma unroll
                for (int c = 0; c < 4; ++c) acc[r][c] = fmaf(av[r], bvv[c], acc[r][c]);
        }
    }
#pragma unroll
    for (int r = 0; r < 4; ++r) {
        const int m = m0 + ty * 4 + r;
#pragma unroll
        for (int c = 0; c < 4; ++c) {
            const int n = n0 + tx * 4 + c;
            if (n < N) {
                float v = acc[r][c] + bias[n];
                if (ACT == 0) v = fmaxf(v, 0.f);
                else v = 1.f / (1.f + expf(-v));
                C[(size_t)m * N + n] = v;
            }
        }
    }
}

// ---------- launcher ----------
extern "C" void kernel_launch(void* const* d_in, const int* in_sizes, int n_in,
                              void* d_out, int out_size, void* d_ws, size_t ws_size,
                              hipStream_t stream) {
    const float* x   = (const float*)d_in[0];
    const float* w1  = (const float*)d_in[1];
    const float* b1  = (const float*)d_in[2];
    const float* w2  = (const float*)d_in[3];
    const float* b2  = (const float*)d_in[4];
    const float* Wc  = (const float*)d_in[5];
    const float* dw1 = (const float*)d_in[6];
    const float* db1 = (const float*)d_in[7];
    const float* dw2 = (const float*)d_in[8];
    const float* db2 = (const float*)d_in[9];
    const float* dw3 = (const float*)d_in[10];
    const float* db3 = (const float*)d_in[11];
    float* out = (float*)d_out;

    char* ws = (char*)d_ws;
    // conv staging (dead after squash_u_k), then reused by UHAT:
    unsigned short* H1T  = (unsigned short*)(ws + 0);          // 52,428,800 B
    unsigned short* W2T  = (unsigned short*)(ws + 52428800);   // 10,616,832 B
    unsigned short* PART = (unsigned short*)(ws + 63045632);   // 18,874,368 B (bf16, z=4)
    unsigned short* UHAT = (unsigned short*)(ws + 0);          // 94,371,840 B (aliases dead staging)
    float* U    = (float*)(ws + 100794368);                    //  9,437,184 B (dead after uhat_k)
    float* BL   = (float*)(ws + 94371840);                     // 11,796,480 B (live iter1->iter2; overlaps dead U tail)
    float* S012 = (float*)(ws + 110231552);                    //    491,520 B (after U; no overlap)
    float* H1D  = (float*)(ws + 94371840);                     //    524,288 B (dead-BL space, after iter2)
    float* H2D  = (float*)(ws + 94896128);                     //  4,194,304 B region

    float* S0 = S012, *S1 = S012 + 40960, *S2 = S012 + 81920;

    conv1_k<<<512, 256, 0, stream>>>(x, w1, b1, H1T);
    w2t_k<<<512, 256, 0, stream>>>(w2, W2T);
    conv2_k<<<1152, 256, 0, stream>>>(H1T, W2T, PART);
    squash_u_k<<<512, 256, 0, stream>>>(PART, b2, U);
    uhat_k<<<1152, 256, 0, stream>>>(Wc, U, UHAT);
    hipMemsetAsync(S012, 0, 3 * 40960 * sizeof(float), stream);
    route_iter0_k<<<dim3(256, 9), 256, 0, stream>>>((const unsigned int*)UHAT, S0);
    route_iter_k<1><<<dim3(256, 9), 256, 0, stream>>>(UHAT, S0, BL, S1);
    route_iter_k<2><<<dim3(256, 9), 256, 0, stream>>>(UHAT, S1, BL, S2);
    final_k<<<256, 512, 0, stream>>>(S2, dw1, db1, out, H1D);
    mlp_k<0><<<dim3(16, 4), 256, 0, stream>>>(H1D, dw2, db2, H2D, 1024, 512);
    mlp_k<1><<<dim3(13, 4), 256, 0, stream>>>(H2D, dw3, db3, out + 2560, 784, 1024);
}

// Round 10
// 519.081 us; speedup vs baseline: 1.0738x; 1.0738x over previous
//
#include <hip/hip_runtime.h>
#include <cstdint>
#include <cstddef>

// ---------- types / helpers ----------
typedef __bf16 bf16x8 __attribute__((ext_vector_type(8)));
typedef float  floatx4 __attribute__((ext_vector_type(4)));
typedef unsigned short ushort8 __attribute__((ext_vector_type(8)));
typedef unsigned short ushort4v __attribute__((ext_vector_type(4)));

__device__ __forceinline__ float bf2f(unsigned short u) {
    union { unsigned int u32; float f; } x; x.u32 = ((unsigned int)u) << 16; return x.f;
}
__device__ __forceinline__ float bflo(unsigned int u) {
    union { unsigned int u32; float f; } x; x.u32 = u << 16; return x.f;
}
__device__ __forceinline__ float bfhi(unsigned int u) {
    union { unsigned int u32; float f; } x; x.u32 = u & 0xffff0000u; return x.f;
}
__device__ __forceinline__ unsigned short f2bf(float f) {
    union { float f; unsigned int u; } x; x.f = f;
    unsigned int u = x.u;
    unsigned int r = (u + 0x7fffu + ((u >> 16) & 1u)) >> 16;   // RNE
    return (unsigned short)r;
}

#define GLOBAL_U32 const __attribute__((address_space(1))) unsigned int*
#define LDS_U32 __attribute__((address_space(3))) unsigned int*
__device__ __forceinline__ void async_cp16(const void* g, void* l) {
    __builtin_amdgcn_global_load_lds((GLOBAL_U32)g, (LDS_U32)l, 16, 0, 0);
}

// ---------- conv1 (oh-split x2): x[256,1,28,28]*w[256,1,9,9] -> h1t bf16 [b][20][20][256] ----------
__global__ __launch_bounds__(256) void conv1_k(const float* __restrict__ x,
                                               const float* __restrict__ w,
                                               const float* __restrict__ bias,
                                               unsigned short* __restrict__ h1t) {
    const int bb = blockIdx.x, t = threadIdx.x;
    const int b = bb >> 1, h = bb & 1;
    const int oh0 = h * 10;
    __shared__ float xs[18 * 28];
    for (int idx = t; idx < 504; idx += 256) xs[idx] = x[b * 784 + oh0 * 28 + idx];
    __syncthreads();
    const float* wr = w + t * 81;   // thread t = output channel t
    const float bv = bias[t];
    for (int ohl = 0; ohl < 10; ++ohl) {
        float acc[20];
#pragma unroll
        for (int ow = 0; ow < 20; ++ow) acc[ow] = bv;
#pragma unroll
        for (int kh = 0; kh < 9; ++kh) {
            float xr[28];
            const float* xrow = &xs[(ohl + kh) * 28];
#pragma unroll
            for (int q = 0; q < 7; ++q) *(float4*)&xr[q * 4] = *(const float4*)&xrow[q * 4];
#pragma unroll
            for (int kw = 0; kw < 9; ++kw) {
                const float wv = wr[kh * 9 + kw];
#pragma unroll
                for (int ow = 0; ow < 20; ++ow) acc[ow] = fmaf(xr[ow + kw], wv, acc[ow]);
            }
        }
        unsigned short* orow = h1t + (size_t)((b * 20 + oh0 + ohl) * 20) * 256 + t;
#pragma unroll
        for (int ow = 0; ow < 20; ++ow) orow[ow * 256] = f2bf(acc[ow]);
    }
}

// ---------- w2 transform: OIHW fp32 [oc][ic][81] -> bf16 [oc][tap*256+ic] ----------
__global__ __launch_bounds__(256) void w2t_k(const float* __restrict__ w2,
                                             unsigned short* __restrict__ w2t) {
    const int oc = blockIdx.x >> 1, half = blockIdx.x & 1, t = threadIdx.x;
    __shared__ float ws[10368];                       // 128 ic * 81 taps
    const float* src = w2 + (size_t)oc * 20736 + half * 128 * 81;
    for (int idx = t; idx < 10368; idx += 256) ws[idx] = src[idx];
    __syncthreads();
    unsigned short* dst = w2t + (size_t)oc * 20736 + half * 128;
    for (int idx = t; idx < 10368; idx += 256) {
        const int tap = idx >> 7, icl = idx & 127;
        dst[tap * 256 + icl] = f2bf(ws[icl * 81 + tap]);
    }
}

// ---------- conv2 implicit GEMM: tile 128M x 64OC, split-K x4, BK=64, swizzled LDS ----------
__device__ __forceinline__ int c2_rowbase(int m) {
    const int b = m / 36, sp = m % 36;
    const int oh = sp / 6, ow = sp % 6;
    return (b * 400 + oh * 40 + ow * 2) * 256;        // element offset into h1t
}

__global__ __launch_bounds__(256) void conv2_k(const unsigned short* __restrict__ h1t,
                                               const unsigned short* __restrict__ w2t,
                                               unsigned short* __restrict__ part) {
    const int t = threadIdx.x;
    // 1152 ids: the 4 bx-siblings of one (by,z) sit 8 apart (same XCD under
    // round-robin) -> A-slice fetched once per XCD; z decorrelated from XCD.
    const int id = blockIdx.x;                        // 0..1151
    const int G = id >> 5;                            // 0..35
    const int bx = (id >> 3) & 3;                     // 0..3 (64-oc tile)
    const int s = id & 7;
    const int by = 2 * G + (s >> 2);                  // 0..71
    const int z  = ((s & 3) + by) & 3;                // 0..3
    __shared__ unsigned short At[128 * 64];           // m rows (16 KB)
    __shared__ unsigned short Bt[64 * 64];            // oc rows (8 KB)

    const int oc0 = bx * 64;

    // staging: A = 4 units/thread, B = 2 units/thread (16B each).
    // LDS slot a; row = a>>3, phys slot sγ = a&7 holds logical unit
    // u = sγ ^ (row&7)  (bank-conflict-free b128 reads).
    int aRB[4], aCU[4], bBase[2];
#pragma unroll
    for (int k = 0; k < 4; ++k) {
        const int a = t + 256 * k;
        const int r = a >> 3, sg = a & 7;
        const int u = sg ^ (r & 7);
        aRB[k] = c2_rowbase(by * 128 + r) + (u & 3) * 8;
        aCU[k] = u >> 2;                              // which chunk of the pair
    }
#pragma unroll
    for (int k = 0; k < 2; ++k) {
        const int a = t + 256 * k;
        const int r = a >> 3, sg = a & 7;             // r in 0..63
        const int u = sg ^ (r & 7);
        bBase[k] = (oc0 + r) * 20736 + (u >> 2) * 32 + (u & 3) * 8;
    }

    const int lane = t & 63, l15 = lane & 15, quad = lane >> 4;
    const int wave = t >> 6;
    const int wM = (wave & 1) * 64, wOC = (wave >> 1) * 32;

    // fragment LDS offsets (ushort units): row stride 64, unit u = h*4+quad
    int aO[2][2], bO[2][4];
#pragma unroll
    for (int i = 0; i < 2; ++i) {
        const int R = wOC + i * 16 + l15;             // oc row (A-operand from Bt)
#pragma unroll
        for (int h = 0; h < 2; ++h)
            aO[h][i] = R * 64 + (((h * 4 + quad) ^ (R & 7)) << 3);
    }
#pragma unroll
    for (int j = 0; j < 4; ++j) {
        const int R = wM + j * 16 + l15;              // m row (B-operand from At)
#pragma unroll
        for (int h = 0; h < 2; ++h)
            bO[h][j] = R * 64 + (((h * 4 + quad) ^ (R & 7)) << 3);
    }

    floatx4 acc[2][4];
#pragma unroll
    for (int i = 0; i < 2; ++i)
#pragma unroll
        for (int j = 0; j < 4; ++j) acc[i][j] = (floatx4){0.f, 0.f, 0.f, 0.f};

    // K = 648 chunks = 324 pairs; split 4 ways: 81 pairs per z
    const int p0 = 81 * z, p1 = p0 + 81;
    for (int p = p0; p < p1; ++p) {
        const int tap = p >> 2;                       // both chunks of a pair share tap
        const int kh = tap / 9, kw = tap - 9 * kh;
        const int aoffB = (kh * 20 + kw) * 256;
        const int ce7 = (2 * p) & 7;
        __syncthreads();
#pragma unroll
        for (int k = 0; k < 4; ++k)
            async_cp16(h1t + aRB[k] + aoffB + (ce7 + aCU[k]) * 32, At + (t + 256 * k) * 8);
#pragma unroll
        for (int k = 0; k < 2; ++k)
            async_cp16(w2t + bBase[k] + p * 64, Bt + (t + 256 * k) * 8);
        __syncthreads();
#pragma unroll
        for (int h = 0; h < 2; ++h) {
            bf16x8 aF[2], bF[4];
#pragma unroll
            for (int i = 0; i < 2; ++i) aF[i] = *(const bf16x8*)(Bt + aO[h][i]);
#pragma unroll
            for (int j = 0; j < 4; ++j) bF[j] = *(const bf16x8*)(At + bO[h][j]);
#pragma unroll
            for (int i = 0; i < 2; ++i)
#pragma unroll
                for (int j = 0; j < 4; ++j)
                    acc[i][j] = __builtin_amdgcn_mfma_f32_16x16x32_bf16(aF[i], bF[j], acc[i][j], 0, 0, 0);
        }
    }

    // epilogue: D[reg->oc][lane->m]; pack 4 bf16 along n, store to PART[z][m][n]
    unsigned short* pz = part + (size_t)z * 2359296;
#pragma unroll
    for (int i = 0; i < 2; ++i) {
        const int n0 = oc0 + wOC + i * 16 + quad * 4;
#pragma unroll
        for (int j = 0; j < 4; ++j) {
            const int m = by * 128 + wM + j * 16 + l15;
            ushort4v pk;
#pragma unroll
            for (int r = 0; r < 4; ++r) pk[r] = f2bf(acc[i][j][r]);
            *(ushort4v*)(pz + (size_t)m * 256 + n0) = pk;
        }
    }
}

// ---------- reduce split-K(bf16 x4) + bias + squash(axis=w) -> u[b][1152][8] (half-split x2) ----------
__global__ __launch_bounds__(256) void squash_u_k(const unsigned short* __restrict__ part,
                                                  const float* __restrict__ bias,
                                                  float* __restrict__ u) {
    const int bb = blockIdx.x, t = threadIdx.x;
    const int b = bb >> 1, h = bb & 1;
    __shared__ float hs[4608];
    const size_t base = (size_t)b * 9216 + h * 4608;
    for (int q = t; q < 2304; q += 256) {
        const int idx = q * 2;
        float v0 = bias[idx & 255], v1 = bias[(idx + 1) & 255];
#pragma unroll
        for (int z = 0; z < 4; ++z) {
            const unsigned int uu = *(const unsigned int*)(part + (size_t)z * 2359296 + base + idx);
            v0 += bflo(uu);
            v1 += bfhi(uu);
        }
        hs[idx] = v0; hs[idx + 1] = v1;
    }
    __syncthreads();
    for (int gq = t; gq < 768; gq += 256) {           // groups (c, oh-local), squash over ow(6)
        const int c = gq / 3, ohl = gq % 3;
        const int oh = h * 3 + ohl;
        float s[6], sq = 0.f;
#pragma unroll
        for (int ow = 0; ow < 6; ++ow) { s[ow] = hs[(ohl * 6 + ow) * 256 + c]; sq = fmaf(s[ow], s[ow], sq); }
        const float norm = sqrtf(sq);
        const float f = (sq / (1.0f + sq)) / (norm + 1e-7f);
        float* up = u + (size_t)b * 9216 + c * 36 + oh * 6;
#pragma unroll
        for (int ow = 0; ow < 6; ++ow) up[ow] = s[ow] * f;
    }
}

// ---------- u_hat[i][b][o*16+d] bf16 = sum_e W[o,i,d,e]*u[b,i,e] ----------
// [i][b] layout: block i writes a contiguous, 128B-aligned 80 KB region.
// No LDS transpose, no partial-line RMW.
__global__ __launch_bounds__(256) void uhat_k(const float* __restrict__ Wc,
                                              const float* __restrict__ u,
                                              unsigned short* __restrict__ uhat) {
    const int i = blockIdx.x, t = threadIdx.x;       // t = b
    __shared__ float Wl[1280];                       // [o][d*8+e]
    for (int idx = t; idx < 1280; idx += 256) {
        const int o = idx >> 7, r = idx & 127;
        Wl[idx] = Wc[((size_t)o * 1152 + i) * 128 + r];
    }
    float ur[8];
    *(float4*)&ur[0] = *(const float4*)(u + (size_t)t * 9216 + i * 8);
    *(float4*)&ur[4] = *(const float4*)(u + (size_t)t * 9216 + i * 8 + 4);
    __syncthreads();
    unsigned short* row = uhat + ((size_t)i * 256 + t) * 160;
#pragma unroll 1
    for (int o = 0; o < 10; ++o) {
        ushort8 v0, v1;
#pragma unroll
        for (int d = 0; d < 8; ++d) {
            const float* wp = &Wl[o * 128 + d * 8];
            float a = 0.f;
#pragma unroll
            for (int e = 0; e < 8; ++e) a = fmaf(wp[e], ur[e], a);
            v0[d] = f2bf(a);
        }
#pragma unroll
        for (int d = 8; d < 16; ++d) {
            const float* wp = &Wl[o * 128 + d * 8];
            float a = 0.f;
#pragma unroll
            for (int e = 0; e < 8; ++e) a = fmaf(wp[e], ur[e], a);
            v1[d - 8] = f2bf(a);
        }
        *(ushort8*)(row + o * 16) = v0;
        *(ushort8*)(row + o * 16 + 8) = v1;
    }
}

// ---------- routing iteration 0: S0[b][160] = 0.1 * sum_i u_hat ----------
__global__ __launch_bounds__(256) void route_iter0_k(const unsigned int* __restrict__ uhat32,
                                                     float* __restrict__ S0) {
    const int b = blockIdx.x, i0 = blockIdx.y * 128, t = threadIdx.x;
    const int th = t & 127, hi = t >> 7;
    if (th >= 80) return;
    // [i][b] layout: column stride per i = 256*80 uints
    const unsigned int* p = uhat32 + ((size_t)(i0 + hi * 64) * 256 + b) * 80 + th;
    float ax = 0.f, ay = 0.f;
#pragma unroll 8
    for (int i = 0; i < 64; ++i) {
        const unsigned int uu = p[(size_t)i * 20480];
        ax += bflo(uu);
        ay += bfhi(uu);
    }
    atomicAdd(&S0[b * 160 + 2 * th], 0.1f * ax);
    atomicAdd(&S0[b * 160 + 2 * th + 1], 0.1f * ay);
}

// ---------- fused routing iteration: squash(S_in) + logit update + softmax + weighted sum ----------
template <int ITER>
__global__ __launch_bounds__(256) void route_iter_k(const unsigned short* __restrict__ uhat,
                                                    const float* __restrict__ S_in,
                                                    float* __restrict__ BL,
                                                    float* __restrict__ S_out) {
    const int b = blockIdx.x, i0 = blockIdx.y * 128, t = threadIdx.x;
    __shared__ __align__(16) unsigned short Ul[128 * 160];   // 40960 B, [i_local][160]
    __shared__ float Vl[160];
    __shared__ float cT[10 * 132];
    __shared__ float dots[128 * 10];

    // stage slab (i0..i0+127, b): rows of 320 B at 80 KB stride.
    // LDS dest is wave-linear (c*16); global address per-lane computed.
    const unsigned short* ub = uhat + ((size_t)i0 * 256 + b) * 160;
#pragma unroll
    for (int rep = 0; rep < 10; ++rep) {
        const int c = rep * 256 + t;
        const int row = c / 20, q = c - row * 20;
        async_cp16(ub + (size_t)row * 40960 + q * 8, (char*)Ul + c * 16);
    }

    // phase 0: squash S_in -> Vl (redundant per block; 160 floats)
    if (t < 160) {
        const float x = S_in[b * 160 + t];
        float sq = x * x;
        sq += __shfl_xor(sq, 1, 16);
        sq += __shfl_xor(sq, 2, 16);
        sq += __shfl_xor(sq, 4, 16);
        sq += __shfl_xor(sq, 8, 16);
        const float norm = sqrtf(sq);
        const float f = (sq / (1.f + sq)) / (norm + 1e-7f);
        Vl[t] = x * f;
    }
    __syncthreads();                                  // drains async + Vl visible

    // p1a mapping: o = t%10 fixed per thread, strip s = t/10 (250 active)
    const int o = t % 10, s = t / 10;
    float vr[16];
    if (t < 250) {
#pragma unroll
        for (int q = 0; q < 4; ++q)
            *(float4*)&vr[q * 4] = *(const float4*)(&Vl[o * 16 + q * 4]);
    }

    // p1a: dots[i][o] = sum_d u_hat[i,o,d] * v[o,d]
    if (t < 250) {
#pragma unroll
        for (int rep = 0; rep < 6; ++rep) {
            const int i = s + 25 * rep;
            if (i < 128) {
                const ushort8 ua = *(const ushort8*)(Ul + i * 160 + o * 16);
                const ushort8 ub2 = *(const ushort8*)(Ul + i * 160 + o * 16 + 8);
                float dot = 0.f;
#pragma unroll
                for (int d = 0; d < 8; ++d) dot = fmaf(bf2f(ua[d]), vr[d], dot);
#pragma unroll
                for (int d = 0; d < 8; ++d) dot = fmaf(bf2f(ub2[d]), vr[8 + d], dot);
                dots[i * 10 + o] = dot;
            }
        }
    }
    __syncthreads();

    // p1b: per-i logits + softmax -> cT[o][i]
    if (t < 128) {
        float bl[10];
#pragma unroll
        for (int oo = 0; oo < 10; ++oo) bl[oo] = dots[t * 10 + oo];
        if (ITER == 2) {
#pragma unroll
            for (int oo = 0; oo < 10; ++oo) bl[oo] += BL[(size_t)b * 11520 + oo * 1152 + i0 + t];
        } else {
#pragma unroll
            for (int oo = 0; oo < 10; ++oo) BL[(size_t)b * 11520 + oo * 1152 + i0 + t] = bl[oo];
        }
        float mx = bl[0];
#pragma unroll
        for (int oo = 1; oo < 10; ++oo) mx = fmaxf(mx, bl[oo]);
        float ex[10], sum = 0.f;
#pragma unroll
        for (int oo = 0; oo < 10; ++oo) { ex[oo] = expf(bl[oo] - mx); sum += ex[oo]; }
        const float inv = 1.f / sum;
#pragma unroll
        for (int oo = 0; oo < 10; ++oo) cT[oo * 132 + t] = ex[oo] * inv;
    }
    __syncthreads();

    // p2: S_out[b][160] += sum_i c[i][o] * u_hat[i][od]  (two 64-i halves)
    const int th = t & 127, hi = t >> 7;
    if (th < 80) {
        const int o8 = th >> 3;
        const unsigned int* base = (const unsigned int*)Ul + (size_t)hi * 64 * 80 + th;
        const float* cb = &cT[o8 * 132 + hi * 64];
        float ax = 0.f, ay = 0.f;
#pragma unroll 4
        for (int ii = 0; ii < 64; ++ii) {
            const float c = cb[ii];
            const unsigned int uu = base[ii * 80];
            ax = fmaf(c, bflo(uu), ax);
            ay = fmaf(c, bfhi(uu), ay);
        }
        atomicAdd(&S_out[b * 160 + 2 * th], ax);
        atomicAdd(&S_out[b * 160 + 2 * th + 1], ay);
    }
}

// ---------- final: squash S2 -> lengths, argmax + fused decoder layer 1 ----------
__global__ __launch_bounds__(512) void final_k(const float* __restrict__ S,
                                               const float* __restrict__ w1,
                                               const float* __restrict__ b1,
                                               float* __restrict__ out_len,
                                               float* __restrict__ h1d) {
    const int b = blockIdx.x, t = threadIdx.x;
    __shared__ float v_s[160];
    __shared__ float len_s[10];
    __shared__ int sel_s;
    if (t < 160) {
        const float x = S[b * 160 + t];
        float sq = x * x;
        sq += __shfl_xor(sq, 1, 16);
        sq += __shfl_xor(sq, 2, 16);
        sq += __shfl_xor(sq, 4, 16);
        sq += __shfl_xor(sq, 8, 16);
        const float norm = sqrtf(sq);
        const float f = (sq / (1.f + sq)) / (norm + 1e-7f);
        v_s[t] = x * f;
        if ((t & 15) == 0) {
            const float len = f * norm;
            len_s[t >> 4] = len;
            out_len[b * 10 + (t >> 4)] = len;
        }
    }
    __syncthreads();
    if (t == 0) {
        float best = len_s[0]; int bi = 0;
        for (int oo = 1; oo < 10; ++oo) if (len_s[oo] > best) { best = len_s[oo]; bi = oo; }
        sel_s = bi;
    }
    __syncthreads();
    const int s = sel_s;
    float acc = b1[t];
    const float* wrow = w1 + (size_t)(s * 16) * 512 + t;
#pragma unroll
    for (int j = 0; j < 16; ++j) acc = fmaf(v_s[s * 16 + j], wrow[j * 512], acc);
    h1d[(size_t)b * 512 + t] = fmaxf(acc, 0.f);
}

// ---------- generic small fp32 GEMM + act (M=256 fixed) ----------
template <int ACT>
__global__ __launch_bounds__(256) void mlp_k(const float* __restrict__ A,
                                             const float* __restrict__ Bm,
                                             const float* __restrict__ bias,
                                             float* __restrict__ C, int N, int K) {
    __shared__ float As[64 * 16];
    __shared__ float Bs[16 * 64];
    const int t = threadIdx.x;
    const int tx = t & 15, ty = t >> 4;
    const int m0 = blockIdx.y * 64, n0 = blockIdx.x * 64;
    float acc[4][4] = {};
    const int arow = t >> 2, ac4 = (t & 3) * 4;
    const int brow = t >> 4, bc4 = (t & 15) * 4;
    for (int k0 = 0; k0 < K; k0 += 16) {
        __syncthreads();
        *(float4*)&As[arow * 16 + ac4] = *(const float4*)&A[(size_t)(m0 + arow) * K + k0 + ac4];
        float4 bv = {0.f, 0.f, 0.f, 0.f};
        const int bn = n0 + bc4;
        if (bn + 3 < N) bv = *(const float4*)&Bm[(size_t)(k0 + brow) * N + bn];
        *(float4*)&Bs[brow * 64 + bc4] = bv;
        __syncthreads();
#pragma unroll
        for (int k = 0; k < 16; ++k) {
            float av[4], bvv[4];
#pragma unroll
            for (int r = 0; r < 4; ++r) av[r] = As[(ty * 4 + r) * 16 + k];
#pragma unroll
            for (int c = 0; c < 4; ++c) bvv[c] = Bs[k * 64 + tx * 4 + c];
#pragma unroll
            for (int r = 0; r < 4; ++r)
#pragma unroll
                for (int c = 0; c < 4; ++c) acc[r][c] = fmaf(av[r], bvv[c], acc[r][c]);
        }
    }
#pragma unroll
    for (int r = 0; r < 4; ++r) {
        const int m = m0 + ty * 4 + r;
#pragma unroll
        for (int c = 0; c < 4; ++c) {
            const int n = n0 + tx * 4 + c;
            if (n < N) {
                float v = acc[r][c] + bias[n];
                if (ACT == 0) v = fmaxf(v, 0.f);
                else v = 1.f / (1.f + expf(-v));
                C[(size_t)m * N + n] = v;
            }
        }
    }
}

// ---------- launcher ----------
extern "C" void kernel_launch(void* const* d_in, const int* in_sizes, int n_in,
                              void* d_out, int out_size, void* d_ws, size_t ws_size,
                              hipStream_t stream) {
    const float* x   = (const float*)d_in[0];
    const float* w1  = (const float*)d_in[1];
    const float* b1  = (const float*)d_in[2];
    const float* w2  = (const float*)d_in[3];
    const float* b2  = (const float*)d_in[4];
    const float* Wc  = (const float*)d_in[5];
    const float* dw1 = (const float*)d_in[6];
    const float* db1 = (const float*)d_in[7];
    const float* dw2 = (const float*)d_in[8];
    const float* db2 = (const float*)d_in[9];
    const float* dw3 = (const float*)d_in[10];
    const float* db3 = (const float*)d_in[11];
    float* out = (float*)d_out;

    char* ws = (char*)d_ws;
    // conv staging (dead after squash_u_k), then reused by UHAT:
    unsigned short* H1T  = (unsigned short*)(ws + 0);          // 52,428,800 B
    unsigned short* W2T  = (unsigned short*)(ws + 52428800);   // 10,616,832 B
    unsigned short* PART = (unsigned short*)(ws + 63045632);   // 18,874,368 B (bf16, z=4)
    unsigned short* UHAT = (unsigned short*)(ws + 0);          // 94,371,840 B [i][b][160] (aliases dead staging)
    float* U    = (float*)(ws + 100794368);                    //  9,437,184 B (dead after uhat_k)
    float* BL   = (float*)(ws + 94371840);                     // 11,796,480 B (live iter1->iter2; overlaps dead U tail)
    float* S012 = (float*)(ws + 110231552);                    //    491,520 B (after U; no overlap)
    float* H1D  = (float*)(ws + 94371840);                     //    524,288 B (dead-BL space, after iter2)
    float* H2D  = (float*)(ws + 94896128);                     //  4,194,304 B region

    float* S0 = S012, *S1 = S012 + 40960, *S2 = S012 + 81920;

    conv1_k<<<512, 256, 0, stream>>>(x, w1, b1, H1T);
    w2t_k<<<512, 256, 0, stream>>>(w2, W2T);
    conv2_k<<<1152, 256, 0, stream>>>(H1T, W2T, PART);
    squash_u_k<<<512, 256, 0, stream>>>(PART, b2, U);
    uhat_k<<<1152, 256, 0, stream>>>(Wc, U, UHAT);
    hipMemsetAsync(S012, 0, 3 * 40960 * sizeof(float), stream);
    route_iter0_k<<<dim3(256, 9), 256, 0, stream>>>((const unsigned int*)UHAT, S0);
    route_iter_k<1><<<dim3(256, 9), 256, 0, stream>>>(UHAT, S0, BL, S1);
    route_iter_k<2><<<dim3(256, 9), 256, 0, stream>>>(UHAT, S1, BL, S2);
    final_k<<<256, 512, 0, stream>>>(S2, dw1, db1, out, H1D);
    mlp_k<0><<<dim3(16, 4), 256, 0, stream>>>(H1D, dw2, db2, H2D, 1024, 512);
    mlp_k<1><<<dim3(13, 4), 256, 0, stream>>>(H2D, dw3, db3, out + 2560, 784, 1024);
}

// Round 11
// 519.079 us; speedup vs baseline: 1.0738x; 1.0000x over previous
//
#include <hip/hip_runtime.h>
#include <cstdint>
#include <cstddef>

// ---------- types / helpers ----------
typedef __bf16 bf16x8 __attribute__((ext_vector_type(8)));
typedef float  floatx4 __attribute__((ext_vector_type(4)));
typedef float  floatx2 __attribute__((ext_vector_type(2)));
typedef unsigned short ushort8 __attribute__((ext_vector_type(8)));
typedef unsigned short ushort4v __attribute__((ext_vector_type(4)));

__device__ __forceinline__ float bf2f(unsigned short u) {
    union { unsigned int u32; float f; } x; x.u32 = ((unsigned int)u) << 16; return x.f;
}
__device__ __forceinline__ float bflo(unsigned int u) {
    union { unsigned int u32; float f; } x; x.u32 = u << 16; return x.f;
}
__device__ __forceinline__ float bfhi(unsigned int u) {
    union { unsigned int u32; float f; } x; x.u32 = u & 0xffff0000u; return x.f;
}
__device__ __forceinline__ unsigned short f2bf(float f) {
    union { float f; unsigned int u; } x; x.f = f;
    unsigned int u = x.u;
    unsigned int r = (u + 0x7fffu + ((u >> 16) & 1u)) >> 16;   // RNE
    return (unsigned short)r;
}
// decode 4 fp8(e4m3) packed in u32 -> 4 floats
__device__ __forceinline__ void fp8x4_dec(unsigned int u, float* f) {
    floatx2 lo = __builtin_amdgcn_cvt_pk_f32_fp8(u, false);
    floatx2 hi = __builtin_amdgcn_cvt_pk_f32_fp8(u, true);
    f[0] = lo[0]; f[1] = lo[1]; f[2] = hi[0]; f[3] = hi[1];
}

#define GLOBAL_U32 const __attribute__((address_space(1))) unsigned int*
#define LDS_U32 __attribute__((address_space(3))) unsigned int*
__device__ __forceinline__ void async_cp16(const void* g, void* l) {
    __builtin_amdgcn_global_load_lds((GLOBAL_U32)g, (LDS_U32)l, 16, 0, 0);
}

#define UHAT_SCALE 64.0f
#define UHAT_INV   (1.0f / 64.0f)

// ---------- conv1 (oh-split x2): x[256,1,28,28]*w[256,1,9,9] -> h1t bf16 [b][20][20][256] ----------
__global__ __launch_bounds__(256) void conv1_k(const float* __restrict__ x,
                                               const float* __restrict__ w,
                                               const float* __restrict__ bias,
                                               unsigned short* __restrict__ h1t) {
    const int bb = blockIdx.x, t = threadIdx.x;
    const int b = bb >> 1, h = bb & 1;
    const int oh0 = h * 10;
    __shared__ float xs[18 * 28];
    for (int idx = t; idx < 504; idx += 256) xs[idx] = x[b * 784 + oh0 * 28 + idx];
    __syncthreads();
    const float* wr = w + t * 81;   // thread t = output channel t
    const float bv = bias[t];
    for (int ohl = 0; ohl < 10; ++ohl) {
        float acc[20];
#pragma unroll
        for (int ow = 0; ow < 20; ++ow) acc[ow] = bv;
#pragma unroll
        for (int kh = 0; kh < 9; ++kh) {
            float xr[28];
            const float* xrow = &xs[(ohl + kh) * 28];
#pragma unroll
            for (int q = 0; q < 7; ++q) *(float4*)&xr[q * 4] = *(const float4*)&xrow[q * 4];
#pragma unroll
            for (int kw = 0; kw < 9; ++kw) {
                const float wv = wr[kh * 9 + kw];
#pragma unroll
                for (int ow = 0; ow < 20; ++ow) acc[ow] = fmaf(xr[ow + kw], wv, acc[ow]);
            }
        }
        unsigned short* orow = h1t + (size_t)((b * 20 + oh0 + ohl) * 20) * 256 + t;
#pragma unroll
        for (int ow = 0; ow < 20; ++ow) orow[ow * 256] = f2bf(acc[ow]);
    }
}

// ---------- w2 transform: OIHW fp32 [oc][ic][81] -> bf16 [oc][tap*256+ic] ----------
__global__ __launch_bounds__(256) void w2t_k(const float* __restrict__ w2,
                                             unsigned short* __restrict__ w2t) {
    const int oc = blockIdx.x >> 1, half = blockIdx.x & 1, t = threadIdx.x;
    __shared__ float ws[10368];                       // 128 ic * 81 taps
    const float* src = w2 + (size_t)oc * 20736 + half * 128 * 81;
    for (int idx = t; idx < 10368; idx += 256) ws[idx] = src[idx];
    __syncthreads();
    unsigned short* dst = w2t + (size_t)oc * 20736 + half * 128;
    for (int idx = t; idx < 10368; idx += 256) {
        const int tap = idx >> 7, icl = idx & 127;
        dst[tap * 256 + icl] = f2bf(ws[icl * 81 + tap]);
    }
}

// ---------- conv2 implicit GEMM: tile 128M x 64OC, split-K x4, BK=64, swizzled LDS ----------
__device__ __forceinline__ int c2_rowbase(int m) {
    const int b = m / 36, sp = m % 36;
    const int oh = sp / 6, ow = sp % 6;
    return (b * 400 + oh * 40 + ow * 2) * 256;        // element offset into h1t
}

__global__ __launch_bounds__(256) void conv2_k(const unsigned short* __restrict__ h1t,
                                               const unsigned short* __restrict__ w2t,
                                               unsigned short* __restrict__ part) {
    const int t = threadIdx.x;
    // 1152 ids: the 4 bx-siblings of one (by,z) sit 8 apart (same XCD under
    // round-robin) -> A-slice fetched once per XCD; z decorrelated from XCD.
    const int id = blockIdx.x;                        // 0..1151
    const int G = id >> 5;                            // 0..35
    const int bx = (id >> 3) & 3;                     // 0..3 (64-oc tile)
    const int s = id & 7;
    const int by = 2 * G + (s >> 2);                  // 0..71
    const int z  = ((s & 3) + by) & 3;                // 0..3
    __shared__ unsigned short At[128 * 64];           // m rows (16 KB)
    __shared__ unsigned short Bt[64 * 64];            // oc rows (8 KB)

    const int oc0 = bx * 64;

    int aRB[4], aCU[4], bBase[2];
#pragma unroll
    for (int k = 0; k < 4; ++k) {
        const int a = t + 256 * k;
        const int r = a >> 3, sg = a & 7;
        const int u = sg ^ (r & 7);
        aRB[k] = c2_rowbase(by * 128 + r) + (u & 3) * 8;
        aCU[k] = u >> 2;                              // which chunk of the pair
    }
#pragma unroll
    for (int k = 0; k < 2; ++k) {
        const int a = t + 256 * k;
        const int r = a >> 3, sg = a & 7;             // r in 0..63
        const int u = sg ^ (r & 7);
        bBase[k] = (oc0 + r) * 20736 + (u >> 2) * 32 + (u & 3) * 8;
    }

    const int lane = t & 63, l15 = lane & 15, quad = lane >> 4;
    const int wave = t >> 6;
    const int wM = (wave & 1) * 64, wOC = (wave >> 1) * 32;

    int aO[2][2], bO[2][4];
#pragma unroll
    for (int i = 0; i < 2; ++i) {
        const int R = wOC + i * 16 + l15;             // oc row (A-operand from Bt)
#pragma unroll
        for (int h = 0; h < 2; ++h)
            aO[h][i] = R * 64 + (((h * 4 + quad) ^ (R & 7)) << 3);
    }
#pragma unroll
    for (int j = 0; j < 4; ++j) {
        const int R = wM + j * 16 + l15;              // m row (B-operand from At)
#pragma unroll
        for (int h = 0; h < 2; ++h)
            bO[h][j] = R * 64 + (((h * 4 + quad) ^ (R & 7)) << 3);
    }

    floatx4 acc[2][4];
#pragma unroll
    for (int i = 0; i < 2; ++i)
#pragma unroll
        for (int j = 0; j < 4; ++j) acc[i][j] = (floatx4){0.f, 0.f, 0.f, 0.f};

    // K = 648 chunks = 324 pairs; split 4 ways: 81 pairs per z
    const int p0 = 81 * z, p1 = p0 + 81;
    for (int p = p0; p < p1; ++p) {
        const int tap = p >> 2;                       // both chunks of a pair share tap
        const int kh = tap / 9, kw = tap - 9 * kh;
        const int aoffB = (kh * 20 + kw) * 256;
        const int ce7 = (2 * p) & 7;
        __syncthreads();
#pragma unroll
        for (int k = 0; k < 4; ++k)
            async_cp16(h1t + aRB[k] + aoffB + (ce7 + aCU[k]) * 32, At + (t + 256 * k) * 8);
#pragma unroll
        for (int k = 0; k < 2; ++k)
            async_cp16(w2t + bBase[k] + p * 64, Bt + (t + 256 * k) * 8);
        __syncthreads();
#pragma unroll
        for (int h = 0; h < 2; ++h) {
            bf16x8 aF[2], bF[4];
#pragma unroll
            for (int i = 0; i < 2; ++i) aF[i] = *(const bf16x8*)(Bt + aO[h][i]);
#pragma unroll
            for (int j = 0; j < 4; ++j) bF[j] = *(const bf16x8*)(At + bO[h][j]);
#pragma unroll
            for (int i = 0; i < 2; ++i)
#pragma unroll
                for (int j = 0; j < 4; ++j)
                    acc[i][j] = __builtin_amdgcn_mfma_f32_16x16x32_bf16(aF[i], bF[j], acc[i][j], 0, 0, 0);
        }
    }

    // epilogue: D[reg->oc][lane->m]; pack 4 bf16 along n, store to PART[z][m][n]
    unsigned short* pz = part + (size_t)z * 2359296;
#pragma unroll
    for (int i = 0; i < 2; ++i) {
        const int n0 = oc0 + wOC + i * 16 + quad * 4;
#pragma unroll
        for (int j = 0; j < 4; ++j) {
            const int m = by * 128 + wM + j * 16 + l15;
            ushort4v pk;
#pragma unroll
            for (int r = 0; r < 4; ++r) pk[r] = f2bf(acc[i][j][r]);
            *(ushort4v*)(pz + (size_t)m * 256 + n0) = pk;
        }
    }
}

// ---------- reduce split-K(bf16 x4) + bias + squash(axis=w) -> u[b][1152][8] (half-split x2) ----------
__global__ __launch_bounds__(256) void squash_u_k(const unsigned short* __restrict__ part,
                                                  const float* __restrict__ bias,
                                                  float* __restrict__ u) {
    const int bb = blockIdx.x, t = threadIdx.x;
    const int b = bb >> 1, h = bb & 1;
    __shared__ float hs[4608];
    const size_t base = (size_t)b * 9216 + h * 4608;
    for (int q = t; q < 2304; q += 256) {
        const int idx = q * 2;
        float v0 = bias[idx & 255], v1 = bias[(idx + 1) & 255];
#pragma unroll
        for (int z = 0; z < 4; ++z) {
            const unsigned int uu = *(const unsigned int*)(part + (size_t)z * 2359296 + base + idx);
            v0 += bflo(uu);
            v1 += bfhi(uu);
        }
        hs[idx] = v0; hs[idx + 1] = v1;
    }
    __syncthreads();
    for (int gq = t; gq < 768; gq += 256) {           // groups (c, oh-local), squash over ow(6)
        const int c = gq / 3, ohl = gq % 3;
        const int oh = h * 3 + ohl;
        float s[6], sq = 0.f;
#pragma unroll
        for (int ow = 0; ow < 6; ++ow) { s[ow] = hs[(ohl * 6 + ow) * 256 + c]; sq = fmaf(s[ow], s[ow], sq); }
        const float norm = sqrtf(sq);
        const float f = (sq / (1.0f + sq)) / (norm + 1e-7f);
        float* up = u + (size_t)b * 9216 + c * 36 + oh * 6;
#pragma unroll
        for (int ow = 0; ow < 6; ++ow) up[ow] = s[ow] * f;
    }
}

// ---------- u_hat fp8: uhat8[i][b][40 u32] = e4m3(64 * W_i u_b) ----------
__global__ __launch_bounds__(256) void uhat_k(const float* __restrict__ Wc,
                                              const float* __restrict__ u,
                                              unsigned int* __restrict__ uhat8) {
    const int i = blockIdx.x, t = threadIdx.x;       // t = b
    __shared__ float Wl[1280];                       // [o][d*8+e]
    for (int idx = t; idx < 1280; idx += 256) {
        const int o = idx >> 7, r = idx & 127;
        Wl[idx] = Wc[((size_t)o * 1152 + i) * 128 + r];
    }
    float ur[8];
    *(float4*)&ur[0] = *(const float4*)(u + (size_t)t * 9216 + i * 8);
    *(float4*)&ur[4] = *(const float4*)(u + (size_t)t * 9216 + i * 8 + 4);
    __syncthreads();
    unsigned int* row = uhat8 + ((size_t)i * 256 + t) * 40;
#pragma unroll 1
    for (int o = 0; o < 10; ++o) {
        float vals[16];
#pragma unroll
        for (int d = 0; d < 16; ++d) {
            const float* wp = &Wl[o * 128 + d * 8];
            float a = 0.f;
#pragma unroll
            for (int e = 0; e < 8; ++e) a = fmaf(wp[e], ur[e], a);
            vals[d] = a * UHAT_SCALE;
        }
        uint4 pk;
        unsigned int w;
#pragma unroll
        for (int q = 0; q < 4; ++q) {
            w = 0;
            w = __builtin_amdgcn_cvt_pk_fp8_f32(vals[q * 4 + 0], vals[q * 4 + 1], w, false);
            w = __builtin_amdgcn_cvt_pk_fp8_f32(vals[q * 4 + 2], vals[q * 4 + 3], w, true);
            if (q == 0) pk.x = w; else if (q == 1) pk.y = w; else if (q == 2) pk.z = w; else pk.w = w;
        }
        *(uint4*)(row + o * 4) = pk;
    }
}

// ---------- routing iteration 0: S0[b][160] = 0.1 * sum_i u_hat ----------
__global__ __launch_bounds__(256) void route_iter0_k(const unsigned int* __restrict__ uhat8,
                                                     float* __restrict__ S0) {
    const int b = blockIdx.x, i0 = blockIdx.y * 128, t = threadIdx.x;
    const int th = t & 127, hi = t >> 7;
    if (th >= 40) return;                             // th = od-quad
    const unsigned int* p = uhat8 + ((size_t)(i0 + hi * 64) * 256 + b) * 40 + th;
    float a0 = 0.f, a1 = 0.f, a2 = 0.f, a3 = 0.f;
#pragma unroll 4
    for (int i = 0; i < 64; ++i) {
        float f[4];
        fp8x4_dec(p[(size_t)i * 10240], f);
        a0 += f[0]; a1 += f[1]; a2 += f[2]; a3 += f[3];
    }
    const float sc = 0.1f * UHAT_INV;
    atomicAdd(&S0[b * 160 + 4 * th + 0], sc * a0);
    atomicAdd(&S0[b * 160 + 4 * th + 1], sc * a1);
    atomicAdd(&S0[b * 160 + 4 * th + 2], sc * a2);
    atomicAdd(&S0[b * 160 + 4 * th + 3], sc * a3);
}

// ---------- fused routing iteration: squash(S_in) + logit update + softmax + weighted sum ----------
template <int ITER>
__global__ __launch_bounds__(256) void route_iter_k(const unsigned int* __restrict__ uhat8,
                                                    const float* __restrict__ S_in,
                                                    float* __restrict__ BL,
                                                    float* __restrict__ S_out) {
    const int b = blockIdx.x, i0 = blockIdx.y * 128, t = threadIdx.x;
    __shared__ __align__(16) unsigned int Ul8[128 * 40];     // 20480 B, [i_local][40 u32]
    __shared__ float Vl[160];
    __shared__ float cT[10 * 132];
    __shared__ float dots[128 * 10];

    // stage slab (i0..i0+127, b): rows of 160 B at 40960 B stride; 1280 16B units.
    const unsigned int* ub = uhat8 + ((size_t)i0 * 256 + b) * 40;
#pragma unroll
    for (int rep = 0; rep < 5; ++rep) {
        const int c = rep * 256 + t;
        const int row = c / 10, q = c - row * 10;
        async_cp16(ub + (size_t)row * 10240 + q * 4, (char*)Ul8 + c * 16);
    }

    // phase 0: squash S_in -> Vl (redundant per block; 160 floats)
    if (t < 160) {
        const float x = S_in[b * 160 + t];
        float sq = x * x;
        sq += __shfl_xor(sq, 1, 16);
        sq += __shfl_xor(sq, 2, 16);
        sq += __shfl_xor(sq, 4, 16);
        sq += __shfl_xor(sq, 8, 16);
        const float norm = sqrtf(sq);
        const float f = (sq / (1.f + sq)) / (norm + 1e-7f);
        Vl[t] = x * f;
    }
    __syncthreads();                                  // drains async + Vl visible

    // p1a mapping: o = t%10 fixed per thread, strip s = t/10 (250 active)
    const int o = t % 10, s = t / 10;
    float vr[16];
    if (t < 250) {
#pragma unroll
        for (int q = 0; q < 4; ++q)
            *(float4*)&vr[q * 4] = *(const float4*)(&Vl[o * 16 + q * 4]);
    }

    // p1a: dots[i][o] = (1/64) * sum_d uq[i,o,d] * v[o,d]
    if (t < 250) {
#pragma unroll
        for (int rep = 0; rep < 6; ++rep) {
            const int i = s + 25 * rep;
            if (i < 128) {
                const uint4 uu = *(const uint4*)(Ul8 + i * 40 + o * 4);
                float f[16];
                fp8x4_dec(uu.x, f);
                fp8x4_dec(uu.y, f + 4);
                fp8x4_dec(uu.z, f + 8);
                fp8x4_dec(uu.w, f + 12);
                float dot = 0.f;
#pragma unroll
                for (int d = 0; d < 16; ++d) dot = fmaf(f[d], vr[d], dot);
                dots[i * 10 + o] = dot * UHAT_INV;
            }
        }
    }
    __syncthreads();

    // p1b: per-i logits + softmax -> cT[o][i]
    if (t < 128) {
        float bl[10];
#pragma unroll
        for (int oo = 0; oo < 10; ++oo) bl[oo] = dots[t * 10 + oo];
        if (ITER == 2) {
#pragma unroll
            for (int oo = 0; oo < 10; ++oo) bl[oo] += BL[(size_t)b * 11520 + oo * 1152 + i0 + t];
        } else {
#pragma unroll
            for (int oo = 0; oo < 10; ++oo) BL[(size_t)b * 11520 + oo * 1152 + i0 + t] = bl[oo];
        }
        float mx = bl[0];
#pragma unroll
        for (int oo = 1; oo < 10; ++oo) mx = fmaxf(mx, bl[oo]);
        float ex[10], sum = 0.f;
#pragma unroll
        for (int oo = 0; oo < 10; ++oo) { ex[oo] = expf(bl[oo] - mx); sum += ex[oo]; }
        const float inv = 1.f / sum;
#pragma unroll
        for (int oo = 0; oo < 10; ++oo) cT[oo * 132 + t] = ex[oo] * inv;
    }
    __syncthreads();

    // p2: S_out[b][160] += (1/64) * sum_i c[i][o] * uq[i][od]  (two 64-i halves)
    const int th = t & 127, hi = t >> 7;
    if (th < 40) {                                    // th = od-quad, o = th>>2
        const int oq = th >> 2;
        const unsigned int* base = Ul8 + hi * 64 * 40 + th;
        const float* cb = &cT[oq * 132 + hi * 64];
        float a0 = 0.f, a1 = 0.f, a2 = 0.f, a3 = 0.f;
#pragma unroll 4
        for (int ii = 0; ii < 64; ++ii) {
            const float c = cb[ii];
            float f[4];
            fp8x4_dec(base[ii * 40], f);
            a0 = fmaf(c, f[0], a0);
            a1 = fmaf(c, f[1], a1);
            a2 = fmaf(c, f[2], a2);
            a3 = fmaf(c, f[3], a3);
        }
        atomicAdd(&S_out[b * 160 + 4 * th + 0], a0 * UHAT_INV);
        atomicAdd(&S_out[b * 160 + 4 * th + 1], a1 * UHAT_INV);
        atomicAdd(&S_out[b * 160 + 4 * th + 2], a2 * UHAT_INV);
        atomicAdd(&S_out[b * 160 + 4 * th + 3], a3 * UHAT_INV);
    }
}

// ---------- final: squash S2 -> lengths, argmax + fused decoder layer 1 ----------
__global__ __launch_bounds__(512) void final_k(const float* __restrict__ S,
                                               const float* __restrict__ w1,
                                               const float* __restrict__ b1,
                                               float* __restrict__ out_len,
                                               float* __restrict__ h1d) {
    const int b = blockIdx.x, t = threadIdx.x;
    __shared__ float v_s[160];
    __shared__ float len_s[10];
    __shared__ int sel_s;
    if (t < 160) {
        const float x = S[b * 160 + t];
        float sq = x * x;
        sq += __shfl_xor(sq, 1, 16);
        sq += __shfl_xor(sq, 2, 16);
        sq += __shfl_xor(sq, 4, 16);
        sq += __shfl_xor(sq, 8, 16);
        const float norm = sqrtf(sq);
        const float f = (sq / (1.f + sq)) / (norm + 1e-7f);
        v_s[t] = x * f;
        if ((t & 15) == 0) {
            const float len = f * norm;
            len_s[t >> 4] = len;
            out_len[b * 10 + (t >> 4)] = len;
        }
    }
    __syncthreads();
    if (t == 0) {
        float best = len_s[0]; int bi = 0;
        for (int oo = 1; oo < 10; ++oo) if (len_s[oo] > best) { best = len_s[oo]; bi = oo; }
        sel_s = bi;
    }
    __syncthreads();
    const int s = sel_s;
    float acc = b1[t];
    const float* wrow = w1 + (size_t)(s * 16) * 512 + t;
#pragma unroll
    for (int j = 0; j < 16; ++j) acc = fmaf(v_s[s * 16 + j], wrow[j * 512], acc);
    h1d[(size_t)b * 512 + t] = fmaxf(acc, 0.f);
}

// ---------- generic small fp32 GEMM + act (M=256 fixed) ----------
template <int ACT>
__global__ __launch_bounds__(256) void mlp_k(const float* __restrict__ A,
                                             const float* __restrict__ Bm,
                                             const float* __restrict__ bias,
                                             float* __restrict__ C, int N, int K) {
    __shared__ float As[64 * 16];
    __shared__ float Bs[16 * 64];
    const int t = threadIdx.x;
    const int tx = t & 15, ty = t >> 4;
    const int m0 = blockIdx.y * 64, n0 = blockIdx.x * 64;
    float acc[4][4] = {};
    const int arow = t >> 2, ac4 = (t & 3) * 4;
    const int brow = t >> 4, bc4 = (t & 15) * 4;
    for (int k0 = 0; k0 < K; k0 += 16) {
        __syncthreads();
        *(float4*)&As[arow * 16 + ac4] = *(const float4*)&A[(size_t)(m0 + arow) * K + k0 + ac4];
        float4 bv = {0.f, 0.f, 0.f, 0.f};
        const int bn = n0 + bc4;
        if (bn + 3 < N) bv = *(const float4*)&Bm[(size_t)(k0 + brow) * N + bn];
        *(float4*)&Bs[brow * 64 + bc4] = bv;
        __syncthreads();
#pragma unroll
        for (int k = 0; k < 16; ++k) {
            float av[4], bvv[4];
#pragma unroll
            for (int r = 0; r < 4; ++r) av[r] = As[(ty * 4 + r) * 16 + k];
#pragma unroll
            for (int c = 0; c < 4; ++c) bvv[c] = Bs[k * 64 + tx * 4 + c];
#pragma unroll
            for (int r = 0; r < 4; ++r)
#pragma unroll
                for (int c = 0; c < 4; ++c) acc[r][c] = fmaf(av[r], bvv[c], acc[r][c]);
        }
    }
#pragma unroll
    for (int r = 0; r < 4; ++r) {
        const int m = m0 + ty * 4 + r;
#pragma unroll
        for (int c = 0; c < 4; ++c) {
            const int n = n0 + tx * 4 + c;
            if (n < N) {
                float v = acc[r][c] + bias[n];
                if (ACT == 0) v = fmaxf(v, 0.f);
                else v = 1.f / (1.f + expf(-v));
                C[(size_t)m * N + n] = v;
            }
        }
    }
}

// ---------- launcher ----------
extern "C" void kernel_launch(void* const* d_in, const int* in_sizes, int n_in,
                              void* d_out, int out_size, void* d_ws, size_t ws_size,
                              hipStream_t stream) {
    const float* x   = (const float*)d_in[0];
    const float* w1  = (const float*)d_in[1];
    const float* b1  = (const float*)d_in[2];
    const float* w2  = (const float*)d_in[3];
    const float* b2  = (const float*)d_in[4];
    const float* Wc  = (const float*)d_in[5];
    const float* dw1 = (const float*)d_in[6];
    const float* db1 = (const float*)d_in[7];
    const float* dw2 = (const float*)d_in[8];
    const float* db2 = (const float*)d_in[9];
    const float* dw3 = (const float*)d_in[10];
    const float* db3 = (const float*)d_in[11];
    float* out = (float*)d_out;

    char* ws = (char*)d_ws;
    // conv staging (dead after squash_u_k), then reused by UHAT (fp8, 47 MB):
    unsigned short* H1T  = (unsigned short*)(ws + 0);          // 52,428,800 B
    unsigned short* W2T  = (unsigned short*)(ws + 52428800);   // 10,616,832 B
    unsigned short* PART = (unsigned short*)(ws + 63045632);   // 18,874,368 B (bf16, z=4)
    unsigned int*   UHAT = (unsigned int*)(ws + 0);            // 47,185,920 B fp8 [i][b][160B]
    float* U    = (float*)(ws + 100794368);                    //  9,437,184 B (dead after uhat_k)
    float* BL   = (float*)(ws + 94371840);                     // 11,796,480 B (live iter1->iter2)
    float* S012 = (float*)(ws + 110231552);                    //    491,520 B
    float* H1D  = (float*)(ws + 94371840);                     //    524,288 B (dead-BL space, after iter2)
    float* H2D  = (float*)(ws + 94896128);                     //  4,194,304 B region

    float* S0 = S012, *S1 = S012 + 40960, *S2 = S012 + 81920;

    conv1_k<<<512, 256, 0, stream>>>(x, w1, b1, H1T);
    w2t_k<<<512, 256, 0, stream>>>(w2, W2T);
    conv2_k<<<1152, 256, 0, stream>>>(H1T, W2T, PART);
    squash_u_k<<<512, 256, 0, stream>>>(PART, b2, U);
    uhat_k<<<1152, 256, 0, stream>>>(Wc, U, UHAT);
    hipMemsetAsync(S012, 0, 3 * 40960 * sizeof(float), stream);
    route_iter0_k<<<dim3(256, 9), 256, 0, stream>>>(UHAT, S0);
    route_iter_k<1><<<dim3(256, 9), 256, 0, stream>>>(UHAT, S0, BL, S1);
    route_iter_k<2><<<dim3(256, 9), 256, 0, stream>>>(UHAT, S1, BL, S2);
    final_k<<<256, 512, 0, stream>>>(S2, dw1, db1, out, H1D);
    mlp_k<0><<<dim3(16, 4), 256, 0, stream>>>(H1D, dw2, db2, H2D, 1024, 512);
    mlp_k<1><<<dim3(13, 4), 256, 0, stream>>>(H2D, dw3, db3, out + 2560, 784, 1024);
}

// Round 12
// 459.563 us; speedup vs baseline: 1.2129x; 1.1295x over previous
//
#include <hip/hip_runtime.h>
#include <cstdint>
#include <cstddef>

// ---------- types / helpers ----------
typedef __bf16 bf16x8 __attribute__((ext_vector_type(8)));
typedef float  floatx4 __attribute__((ext_vector_type(4)));
typedef float  floatx2 __attribute__((ext_vector_type(2)));
typedef unsigned short ushort8 __attribute__((ext_vector_type(8)));
typedef unsigned short ushort4v __attribute__((ext_vector_type(4)));

__device__ __forceinline__ float bflo(unsigned int u) {
    union { unsigned int u32; float f; } x; x.u32 = u << 16; return x.f;
}
__device__ __forceinline__ float bfhi(unsigned int u) {
    union { unsigned int u32; float f; } x; x.u32 = u & 0xffff0000u; return x.f;
}
__device__ __forceinline__ unsigned short f2bf(float f) {
    union { float f; unsigned int u; } x; x.f = f;
    unsigned int u = x.u;
    unsigned int r = (u + 0x7fffu + ((u >> 16) & 1u)) >> 16;   // RNE
    return (unsigned short)r;
}
__device__ __forceinline__ unsigned char f2fp8(float f) {
    unsigned int pk = __builtin_amdgcn_cvt_pk_fp8_f32(f, f, 0, false);
    return (unsigned char)(pk & 0xff);
}
// decode 4 fp8(e4m3) packed in u32 -> 4 floats
__device__ __forceinline__ void fp8x4_dec(unsigned int u, float* f) {
    floatx2 lo = __builtin_amdgcn_cvt_pk_f32_fp8(u, false);
    floatx2 hi = __builtin_amdgcn_cvt_pk_f32_fp8(u, true);
    f[0] = lo[0]; f[1] = lo[1]; f[2] = hi[0]; f[3] = hi[1];
}

#define GLOBAL_U32 const __attribute__((address_space(1))) unsigned int*
#define LDS_U32 __attribute__((address_space(3))) unsigned int*
__device__ __forceinline__ void async_cp16(const void* g, void* l) {
    __builtin_amdgcn_global_load_lds((GLOBAL_U32)g, (LDS_U32)l, 16, 0, 0);
}

#define UHAT_SCALE 64.0f
#define UHAT_INV   (1.0f / 64.0f)
#define W2_SCALE   16.0f
#define W2_INV     (1.0f / 16.0f)

// ---------- prep: conv1 (blocks 0..511) + w2t fp8 (blocks 512..1023) + S012 zero ----------
__global__ __launch_bounds__(256) void prep_k(const float* __restrict__ x,
                                              const float* __restrict__ w1c,
                                              const float* __restrict__ b1c,
                                              const float* __restrict__ w2,
                                              unsigned char* __restrict__ h1t8,
                                              unsigned char* __restrict__ w2t8,
                                              float* __restrict__ S012) {
    const int blk = blockIdx.x, t = threadIdx.x;
    // zero routing accumulators: 122880 floats = 1024 blocks x 120
    if (t < 120) S012[blk * 120 + t] = 0.f;
    __shared__ float shm[10368];
    if (blk < 512) {
        // conv1 (oh-split x2): x[256,1,28,28]*w[256,1,9,9] -> h1t8 fp8 [b][20][20][256]
        const int b = blk >> 1, hh = blk & 1;
        const int oh0 = hh * 10;
        for (int idx = t; idx < 504; idx += 256) shm[idx] = x[b * 784 + oh0 * 28 + idx];
        __syncthreads();
        const float* wr = w1c + t * 81;               // thread t = output channel t
        const float bv = b1c[t];
        for (int ohl = 0; ohl < 10; ++ohl) {
            float acc[20];
#pragma unroll
            for (int ow = 0; ow < 20; ++ow) acc[ow] = bv;
#pragma unroll
            for (int kh = 0; kh < 9; ++kh) {
                float xr[28];
                const float* xrow = &shm[(ohl + kh) * 28];
#pragma unroll
                for (int q = 0; q < 7; ++q) *(float4*)&xr[q * 4] = *(const float4*)&xrow[q * 4];
#pragma unroll
                for (int kw = 0; kw < 9; ++kw) {
                    const float wv = wr[kh * 9 + kw];
#pragma unroll
                    for (int ow = 0; ow < 20; ++ow) acc[ow] = fmaf(xr[ow + kw], wv, acc[ow]);
                }
            }
            unsigned char* orow = h1t8 + (size_t)((b * 20 + oh0 + ohl) * 20) * 256 + t;
#pragma unroll
            for (int ow = 0; ow < 20; ++ow) orow[ow * 256] = f2fp8(acc[ow]);
        }
    } else {
        // w2 transform: OIHW fp32 [oc][ic][81] -> fp8 [oc][tap*256+ic], x16 scale
        const int id = blk - 512;
        const int oc = id >> 1, half = id & 1;
        const float* src = w2 + (size_t)oc * 20736 + half * 128 * 81;
        for (int idx = t; idx < 10368; idx += 256) shm[idx] = src[idx];
        __syncthreads();
        unsigned char* dst = w2t8 + (size_t)oc * 20736 + half * 128;
        for (int idx = t; idx < 10368; idx += 256) {
            const int tap = idx >> 7, icl = idx & 127;
            dst[tap * 256 + icl] = f2fp8(shm[icl * 81 + tap] * W2_SCALE);
        }
    }
}

// ---------- conv2 implicit GEMM fp8: tile 128M x 64OC, split-K x4, BK=128, swizzled LDS ----------
__device__ __forceinline__ int c2_rowbase(int m) {
    const int b = m / 36, sp = m % 36;
    const int oh = sp / 6, ow = sp % 6;
    return (b * 400 + oh * 40 + ow * 2) * 256;        // byte offset into h1t8 (1 B/elem)
}

__global__ __launch_bounds__(256) void conv2_k(const unsigned char* __restrict__ h1t8,
                                               const unsigned char* __restrict__ w2t8,
                                               unsigned short* __restrict__ part) {
    const int t = threadIdx.x;
    // 1152 ids: 4 bx-siblings of one (by,z) sit 8 apart (same XCD) -> A-slice
    // fetched once per XCD; z decorrelated from XCD. Verified bijection.
    const int id = blockIdx.x;                        // 0..1151
    const int G = id >> 5;                            // 0..35
    const int bx = (id >> 3) & 3;                     // 0..3 (64-oc tile)
    const int s = id & 7;
    const int by = 2 * G + (s >> 2);                  // 0..71
    const int z  = ((s & 3) + by) & 3;                // 0..3
    __shared__ unsigned char At[128 * 128];           // m rows, 128 fp8 (16 KB)
    __shared__ unsigned char Bt[64 * 128];            // oc rows (8 KB)

    const int oc0 = bx * 64;

    // staging: A = 4 units/thread, B = 2 units/thread (16 B each).
    // unit a; row r = a>>3, phys slot sg = a&7 holds logical u = sg ^ (r&7).
    int aRB[4], bBase[2];
#pragma unroll
    for (int k = 0; k < 4; ++k) {
        const int a = t + 256 * k;
        const int r = a >> 3, sg = a & 7;
        const int u = sg ^ (r & 7);
        aRB[k] = c2_rowbase(by * 128 + r) + u * 16;
    }
#pragma unroll
    for (int k = 0; k < 2; ++k) {
        const int a = t + 256 * k;
        const int r = a >> 3, sg = a & 7;             // r in 0..63
        const int u = sg ^ (r & 7);
        bBase[k] = (oc0 + r) * 20736 + u * 16;
    }

    const int lane = t & 63, l15 = lane & 15, quad = lane >> 4;
    const int wave = t >> 6;
    const int wM = (wave & 1) * 64, wOC = (wave >> 1) * 32;

    // fragment LDS byte offsets: row stride 128, step h: u_log = 2h+(quad>>1),
    // byte = R*128 + ((u_log ^ (R&7))<<4) + 8*(quad&1)   (b64 reads, 2-way max)
    int aO[4][2], bO[4][4];
#pragma unroll
    for (int i = 0; i < 2; ++i) {
        const int R = wOC + i * 16 + l15;             // oc row (A-operand from Bt)
#pragma unroll
        for (int h = 0; h < 4; ++h)
            aO[h][i] = R * 128 + (((2 * h + (quad >> 1)) ^ (R & 7)) << 4) + 8 * (quad & 1);
    }
#pragma unroll
    for (int j = 0; j < 4; ++j) {
        const int R = wM + j * 16 + l15;              // m row (B-operand from At)
#pragma unroll
        for (int h = 0; h < 4; ++h)
            bO[h][j] = R * 128 + (((2 * h + (quad >> 1)) ^ (R & 7)) << 4) + 8 * (quad & 1);
    }

    floatx4 acc[2][4];
#pragma unroll
    for (int i = 0; i < 2; ++i)
#pragma unroll
        for (int j = 0; j < 4; ++j) acc[i][j] = (floatx4){0.f, 0.f, 0.f, 0.f};

    // K = 20736 = 162 quads of 128; split 4 ways: 40/41/40/41
    const int q0 = (162 * z) >> 2, q1 = (162 * (z + 1)) >> 2;
    for (int q = q0; q < q1; ++q) {
        const int tap = q >> 1;                       // BK=128 = half a tap; never crosses
        const int kh = tap / 9, kw = tap - 9 * kh;
        const int aoffB = (kh * 20 + kw) * 256 + (q & 1) * 128;
        __syncthreads();
#pragma unroll
        for (int k = 0; k < 4; ++k)
            async_cp16(h1t8 + aRB[k] + aoffB, At + (t + 256 * k) * 16);
#pragma unroll
        for (int k = 0; k < 2; ++k)
            async_cp16(w2t8 + bBase[k] + q * 128, Bt + (t + 256 * k) * 16);
        __syncthreads();
#pragma unroll
        for (int h = 0; h < 4; ++h) {
            long aF[2], bF[4];
#pragma unroll
            for (int i = 0; i < 2; ++i) aF[i] = *(const long*)(Bt + aO[h][i]);
#pragma unroll
            for (int j = 0; j < 4; ++j) bF[j] = *(const long*)(At + bO[h][j]);
#pragma unroll
            for (int i = 0; i < 2; ++i)
#pragma unroll
                for (int j = 0; j < 4; ++j)
                    acc[i][j] = __builtin_amdgcn_mfma_f32_16x16x32_fp8_fp8(aF[i], bF[j], acc[i][j], 0, 0, 0);
        }
    }

    // epilogue: D[reg->oc][lane->m]; undo W2 scale; pack 4 bf16 along n -> PART[z][m][n]
    unsigned short* pz = part + (size_t)z * 2359296;
#pragma unroll
    for (int i = 0; i < 2; ++i) {
        const int n0 = oc0 + wOC + i * 16 + quad * 4;
#pragma unroll
        for (int j = 0; j < 4; ++j) {
            const int m = by * 128 + wM + j * 16 + l15;
            ushort4v pk;
#pragma unroll
            for (int r = 0; r < 4; ++r) pk[r] = f2bf(acc[i][j][r] * W2_INV);
            *(ushort4v*)(pz + (size_t)m * 256 + n0) = pk;
        }
    }
}

// ---------- reduce split-K(bf16 x4) + bias + squash(axis=w) -> u[b][1152][8] (half-split x2) ----------
__global__ __launch_bounds__(256) void squash_u_k(const unsigned short* __restrict__ part,
                                                  const float* __restrict__ bias,
                                                  float* __restrict__ u) {
    const int bb = blockIdx.x, t = threadIdx.x;
    const int b = bb >> 1, h = bb & 1;
    __shared__ float hs[4608];
    const size_t base = (size_t)b * 9216 + h * 4608;
    for (int q = t; q < 2304; q += 256) {
        const int idx = q * 2;
        float v0 = bias[idx & 255], v1 = bias[(idx + 1) & 255];
#pragma unroll
        for (int z = 0; z < 4; ++z) {
            const unsigned int uu = *(const unsigned int*)(part + (size_t)z * 2359296 + base + idx);
            v0 += bflo(uu);
            v1 += bfhi(uu);
        }
        hs[idx] = v0; hs[idx + 1] = v1;
    }
    __syncthreads();
    for (int gq = t; gq < 768; gq += 256) {           // groups (c, oh-local), squash over ow(6)
        const int c = gq / 3, ohl = gq % 3;
        const int oh = h * 3 + ohl;
        float s[6], sq = 0.f;
#pragma unroll
        for (int ow = 0; ow < 6; ++ow) { s[ow] = hs[(ohl * 6 + ow) * 256 + c]; sq = fmaf(s[ow], s[ow], sq); }
        const float norm = sqrtf(sq);
        const float f = (sq / (1.0f + sq)) / (norm + 1e-7f);
        float* up = u + (size_t)b * 9216 + c * 36 + oh * 6;
#pragma unroll
        for (int ow = 0; ow < 6; ++ow) up[ow] = s[ow] * f;
    }
}

// ---------- u_hat fp8: uhat8[i][b][40 u32] = e4m3(64 * W_i u_b) ----------
__global__ __launch_bounds__(256) void uhat_k(const float* __restrict__ Wc,
                                              const float* __restrict__ u,
                                              unsigned int* __restrict__ uhat8) {
    const int i = blockIdx.x, t = threadIdx.x;       // t = b
    __shared__ float Wl[1280];                       // [o][d*8+e]
    for (int idx = t; idx < 1280; idx += 256) {
        const int o = idx >> 7, r = idx & 127;
        Wl[idx] = Wc[((size_t)o * 1152 + i) * 128 + r];
    }
    float ur[8];
    *(float4*)&ur[0] = *(const float4*)(u + (size_t)t * 9216 + i * 8);
    *(float4*)&ur[4] = *(const float4*)(u + (size_t)t * 9216 + i * 8 + 4);
    __syncthreads();
    unsigned int* row = uhat8 + ((size_t)i * 256 + t) * 40;
#pragma unroll 1
    for (int o = 0; o < 10; ++o) {
        float vals[16];
#pragma unroll
        for (int d = 0; d < 16; ++d) {
            const float* wp = &Wl[o * 128 + d * 8];
            float a = 0.f;
#pragma unroll
            for (int e = 0; e < 8; ++e) a = fmaf(wp[e], ur[e], a);
            vals[d] = a * UHAT_SCALE;
        }
        uint4 pk;
        unsigned int w;
#pragma unroll
        for (int q = 0; q < 4; ++q) {
            w = 0;
            w = __builtin_amdgcn_cvt_pk_fp8_f32(vals[q * 4 + 0], vals[q * 4 + 1], w, false);
            w = __builtin_amdgcn_cvt_pk_fp8_f32(vals[q * 4 + 2], vals[q * 4 + 3], w, true);
            if (q == 0) pk.x = w; else if (q == 1) pk.y = w; else if (q == 2) pk.z = w; else pk.w = w;
        }
        *(uint4*)(row + o * 4) = pk;
    }
}

// ---------- routing iteration 0: S0[b][160] = 0.1 * sum_i u_hat ----------
__global__ __launch_bounds__(256) void route_iter0_k(const unsigned int* __restrict__ uhat8,
                                                     float* __restrict__ S0) {
    const int b = blockIdx.x, i0 = blockIdx.y * 128, t = threadIdx.x;
    const int th = t & 127, hi = t >> 7;
    if (th >= 40) return;                             // th = od-quad
    const unsigned int* p = uhat8 + ((size_t)(i0 + hi * 64) * 256 + b) * 40 + th;
    float a0 = 0.f, a1 = 0.f, a2 = 0.f, a3 = 0.f;
#pragma unroll 4
    for (int i = 0; i < 64; ++i) {
        float f[4];
        fp8x4_dec(p[(size_t)i * 10240], f);
        a0 += f[0]; a1 += f[1]; a2 += f[2]; a3 += f[3];
    }
    const float sc = 0.1f * UHAT_INV;
    atomicAdd(&S0[b * 160 + 4 * th + 0], sc * a0);
    atomicAdd(&S0[b * 160 + 4 * th + 1], sc * a1);
    atomicAdd(&S0[b * 160 + 4 * th + 2], sc * a2);
    atomicAdd(&S0[b * 160 + 4 * th + 3], sc * a3);
}

// ---------- fused routing iteration: squash(S_in) + logit update + softmax + weighted sum ----------
template <int ITER>
__global__ __launch_bounds__(256) void route_iter_k(const unsigned int* __restrict__ uhat8,
                                                    const float* __restrict__ S_in,
                                                    float* __restrict__ BL,
                                                    float* __restrict__ S_out) {
    const int b = blockIdx.x, i0 = blockIdx.y * 128, t = threadIdx.x;
    __shared__ __align__(16) unsigned int Ul8[128 * 40];     // 20480 B, [i_local][40 u32]
    __shared__ float Vl[160];
    __shared__ float cT[10 * 132];
    __shared__ float dots[128 * 10];

    // stage slab (i0..i0+127, b): rows of 160 B at 40960 B stride; 1280 16B units.
    const unsigned int* ub = uhat8 + ((size_t)i0 * 256 + b) * 40;
#pragma unroll
    for (int rep = 0; rep < 5; ++rep) {
        const int c = rep * 256 + t;
        const int row = c / 10, q = c - row * 10;
        async_cp16(ub + (size_t)row * 10240 + q * 4, (char*)Ul8 + c * 16);
    }

    // phase 0: squash S_in -> Vl (redundant per block; 160 floats)
    if (t < 160) {
        const float x = S_in[b * 160 + t];
        float sq = x * x;
        sq += __shfl_xor(sq, 1, 16);
        sq += __shfl_xor(sq, 2, 16);
        sq += __shfl_xor(sq, 4, 16);
        sq += __shfl_xor(sq, 8, 16);
        const float norm = sqrtf(sq);
        const float f = (sq / (1.f + sq)) / (norm + 1e-7f);
        Vl[t] = x * f;
    }
    __syncthreads();                                  // drains async + Vl visible

    // p1a mapping: o = t%10 fixed per thread, strip s = t/10 (250 active)
    const int o = t % 10, s = t / 10;
    float vr[16];
    if (t < 250) {
#pragma unroll
        for (int q = 0; q < 4; ++q)
            *(float4*)&vr[q * 4] = *(const float4*)(&Vl[o * 16 + q * 4]);
    }

    // p1a: dots[i][o] = (1/64) * sum_d uq[i,o,d] * v[o,d]
    if (t < 250) {
#pragma unroll
        for (int rep = 0; rep < 6; ++rep) {
            const int i = s + 25 * rep;
            if (i < 128) {
                const uint4 uu = *(const uint4*)(Ul8 + i * 40 + o * 4);
                float f[16];
                fp8x4_dec(uu.x, f);
                fp8x4_dec(uu.y, f + 4);
                fp8x4_dec(uu.z, f + 8);
                fp8x4_dec(uu.w, f + 12);
                float dot = 0.f;
#pragma unroll
                for (int d = 0; d < 16; ++d) dot = fmaf(f[d], vr[d], dot);
                dots[i * 10 + o] = dot * UHAT_INV;
            }
        }
    }
    __syncthreads();

    // p1b: per-i logits + softmax -> cT[o][i]
    if (t < 128) {
        float bl[10];
#pragma unroll
        for (int oo = 0; oo < 10; ++oo) bl[oo] = dots[t * 10 + oo];
        if (ITER == 2) {
#pragma unroll
            for (int oo = 0; oo < 10; ++oo) bl[oo] += BL[(size_t)b * 11520 + oo * 1152 + i0 + t];
        } else {
#pragma unroll
            for (int oo = 0; oo < 10; ++oo) BL[(size_t)b * 11520 + oo * 1152 + i0 + t] = bl[oo];
        }
        float mx = bl[0];
#pragma unroll
        for (int oo = 1; oo < 10; ++oo) mx = fmaxf(mx, bl[oo]);
        float ex[10], sum = 0.f;
#pragma unroll
        for (int oo = 0; oo < 10; ++oo) { ex[oo] = expf(bl[oo] - mx); sum += ex[oo]; }
        const float inv = 1.f / sum;
#pragma unroll
        for (int oo = 0; oo < 10; ++oo) cT[oo * 132 + t] = ex[oo] * inv;
    }
    __syncthreads();

    // p2: S_out[b][160] += (1/64) * sum_i c[i][o] * uq[i][od]  (two 64-i halves)
    const int th = t & 127, hi = t >> 7;
    if (th < 40) {                                    // th = od-quad, o = th>>2
        const int oq = th >> 2;
        const unsigned int* base = Ul8 + hi * 64 * 40 + th;
        const float* cb = &cT[oq * 132 + hi * 64];
        float a0 = 0.f, a1 = 0.f, a2 = 0.f, a3 = 0.f;
#pragma unroll 4
        for (int ii = 0; ii < 64; ++ii) {
            const float c = cb[ii];
            float f[4];
            fp8x4_dec(base[ii * 40], f);
            a0 = fmaf(c, f[0], a0);
            a1 = fmaf(c, f[1], a1);
            a2 = fmaf(c, f[2], a2);
            a3 = fmaf(c, f[3], a3);
        }
        atomicAdd(&S_out[b * 160 + 4 * th + 0], a0 * UHAT_INV);
        atomicAdd(&S_out[b * 160 + 4 * th + 1], a1 * UHAT_INV);
        atomicAdd(&S_out[b * 160 + 4 * th + 2], a2 * UHAT_INV);
        atomicAdd(&S_out[b * 160 + 4 * th + 3], a3 * UHAT_INV);
    }
}

// ---------- final: squash S2 -> lengths, argmax + fused decoder layer 1 ----------
__global__ __launch_bounds__(512) void final_k(const float* __restrict__ S,
                                               const float* __restrict__ w1,
                                               const float* __restrict__ b1,
                                               float* __restrict__ out_len,
                                               float* __restrict__ h1d) {
    const int b = blockIdx.x, t = threadIdx.x;
    __shared__ float v_s[160];
    __shared__ float len_s[10];
    __shared__ int sel_s;
    if (t < 160) {
        const float x = S[b * 160 + t];
        float sq = x * x;
        sq += __shfl_xor(sq, 1, 16);
        sq += __shfl_xor(sq, 2, 16);
        sq += __shfl_xor(sq, 4, 16);
        sq += __shfl_xor(sq, 8, 16);
        const float norm = sqrtf(sq);
        const float f = (sq / (1.f + sq)) / (norm + 1e-7f);
        v_s[t] = x * f;
        if ((t & 15) == 0) {
            const float len = f * norm;
            len_s[t >> 4] = len;
            out_len[b * 10 + (t >> 4)] = len;
        }
    }
    __syncthreads();
    if (t == 0) {
        float best = len_s[0]; int bi = 0;
        for (int oo = 1; oo < 10; ++oo) if (len_s[oo] > best) { best = len_s[oo]; bi = oo; }
        sel_s = bi;
    }
    __syncthreads();
    const int s = sel_s;
    float acc = b1[t];
    const float* wrow = w1 + (size_t)(s * 16) * 512 + t;
#pragma unroll
    for (int j = 0; j < 16; ++j) acc = fmaf(v_s[s * 16 + j], wrow[j * 512], acc);
    h1d[(size_t)b * 512 + t] = fmaxf(acc, 0.f);
}

// ---------- generic small fp32 GEMM + act (M=256 fixed) ----------
template <int ACT>
__global__ __launch_bounds__(256) void mlp_k(const float* __restrict__ A,
                                             const float* __restrict__ Bm,
                                             const float* __restrict__ bias,
                                             float* __restrict__ C, int N, int K) {
    __shared__ float As[64 * 16];
    __shared__ float Bs[16 * 64];
    const int t = threadIdx.x;
    const int tx = t & 15, ty = t >> 4;
    const int m0 = blockIdx.y * 64, n0 = blockIdx.x * 64;
    float acc[4][4] = {};
    const int arow = t >> 2, ac4 = (t & 3) * 4;
    const int brow = t >> 4, bc4 = (t & 15) * 4;
    for (int k0 = 0; k0 < K; k0 += 16) {
        __syncthreads();
        *(float4*)&As[arow * 16 + ac4] = *(const float4*)&A[(size_t)(m0 + arow) * K + k0 + ac4];
        float4 bv = {0.f, 0.f, 0.f, 0.f};
        const int bn = n0 + bc4;
        if (bn + 3 < N) bv = *(const float4*)&Bm[(size_t)(k0 + brow) * N + bn];
        *(float4*)&Bs[brow * 64 + bc4] = bv;
        __syncthreads();
#pragma unroll
        for (int k = 0; k < 16; ++k) {
            float av[4], bvv[4];
#pragma unroll
            for (int r = 0; r < 4; ++r) av[r] = As[(ty * 4 + r) * 16 + k];
#pragma unroll
            for (int c = 0; c < 4; ++c) bvv[c] = Bs[k * 64 + tx * 4 + c];
#pragma unroll
            for (int r = 0; r < 4; ++r)
#pragma unroll
                for (int c = 0; c < 4; ++c) acc[r][c] = fmaf(av[r], bvv[c], acc[r][c]);
        }
    }
#pragma unroll
    for (int r = 0; r < 4; ++r) {
        const int m = m0 + ty * 4 + r;
#pragma unroll
        for (int c = 0; c < 4; ++c) {
            const int n = n0 + tx * 4 + c;
            if (n < N) {
                float v = acc[r][c] + bias[n];
                if (ACT == 0) v = fmaxf(v, 0.f);
                else v = 1.f / (1.f + expf(-v));
                C[(size_t)m * N + n] = v;
            }
        }
    }
}

// ---------- launcher ----------
extern "C" void kernel_launch(void* const* d_in, const int* in_sizes, int n_in,
                              void* d_out, int out_size, void* d_ws, size_t ws_size,
                              hipStream_t stream) {
    const float* x   = (const float*)d_in[0];
    const float* w1  = (const float*)d_in[1];
    const float* b1  = (const float*)d_in[2];
    const float* w2  = (const float*)d_in[3];
    const float* b2  = (const float*)d_in[4];
    const float* Wc  = (const float*)d_in[5];
    const float* dw1 = (const float*)d_in[6];
    const float* db1 = (const float*)d_in[7];
    const float* dw2 = (const float*)d_in[8];
    const float* db2 = (const float*)d_in[9];
    const float* dw3 = (const float*)d_in[10];
    const float* db3 = (const float*)d_in[11];
    float* out = (float*)d_out;

    char* ws = (char*)d_ws;
    unsigned char* H1T8 = (unsigned char*)(ws + 0);            // 26,214,400 B fp8
    unsigned char* W2T8 = (unsigned char*)(ws + 26214400);     //  5,308,416 B fp8 (x16)
    unsigned short* PART = (unsigned short*)(ws + 31522816);   // 18,874,368 B bf16, z=4
    unsigned int*   UHAT = (unsigned int*)(ws + 0);            // 47,185,920 B fp8 (aliases dead staging)
    float* U    = (float*)(ws + 50397184);                     //  9,437,184 B (after PART; dead after uhat_k)
    float* BL   = (float*)(ws + 59834368);                     // 11,796,480 B (live iter1->iter2)
    float* S012 = (float*)(ws + 71630848);                     //    491,520 B (zeroed by prep_k)
    float* H1D  = (float*)(ws + 59834368);                     //    524,288 B (dead-BL space, after iter2)
    float* H2D  = (float*)(ws + 60358656);                     //  1,048,576 B

    float* S0 = S012, *S1 = S012 + 40960, *S2 = S012 + 81920;

    prep_k<<<1024, 256, 0, stream>>>(x, w1, b1, w2, H1T8, W2T8, S012);
    conv2_k<<<1152, 256, 0, stream>>>(H1T8, W2T8, PART);
    squash_u_k<<<512, 256, 0, stream>>>(PART, b2, U);
    uhat_k<<<1152, 256, 0, stream>>>(Wc, U, UHAT);
    route_iter0_k<<<dim3(256, 9), 256, 0, stream>>>(UHAT, S0);
    route_iter_k<1><<<dim3(256, 9), 256, 0, stream>>>(UHAT, S0, BL, S1);
    route_iter_k<2><<<dim3(256, 9), 256, 0, stream>>>(UHAT, S1, BL, S2);
    final_k<<<256, 512, 0, stream>>>(S2, dw1, db1, out, H1D);
    mlp_k<0><<<dim3(16, 4), 256, 0, stream>>>(H1D, dw2, db2, H2D, 1024, 512);
    mlp_k<1><<<dim3(13, 4), 256, 0, stream>>>(H2D, dw3, db3, out + 2560, 784, 1024);
}